// Round 4
// baseline (2654.561 us; speedup 1.0000x reference)
//
#include <hip/hip_runtime.h>
#include <math.h>

// ============================================================================
// RetrievalAugmentedProcessor — MI355X (gfx950)
// B=4 S=2048 D=1024 R=3 K=256 MAXR=256 H=8 HD=128
// R4: fix R3's workspace aliasing bug — seltok/kbuf/VT are 2 MB each
//     ([4][256][1024] bf16) but were given 1 MB slots: k-proj GEMM raced with
//     seltok reads (batches 2-3) and VT clobbered kbuf -> absmax 0.73.
//     Now seltok@48, kbuf@50, VT@52 (region 46..56 free). All else = R3:
//     split-bf16 (hi+lo, 3xMFMA) through the selection-feeding chain,
//     fp32 pooling scores/h, plain bf16 stage F.
// ============================================================================

typedef unsigned short u16;
typedef unsigned int   u32;
typedef __attribute__((ext_vector_type(8))) short short8;   // 8 bf16
typedef __attribute__((ext_vector_type(4))) float f32x4;    // MFMA acc
typedef __attribute__((ext_vector_type(4))) u16  u16x4;

__device__ __forceinline__ float b2f(u16 u){ union{float f;u32 i;} x; x.i=((u32)u)<<16; return x.f; }
__device__ __forceinline__ u16 f2b(float f){ union{float f;u32 i;} x; x.f=f; u32 r=x.i+0x7fffu+((x.i>>16)&1u); return (u16)(r>>16); }
__device__ __forceinline__ float gelu_f(float v){ return 0.5f*v*(1.f+erff(v*0.70710678118654752f)); }

// ---------------- reductions ----------------
__device__ __forceinline__ float waveRedSum(float v){
  #pragma unroll
  for (int o=32;o>0;o>>=1) v += __shfl_xor(v,o);
  return v;
}
__device__ __forceinline__ float waveRedMax(float v){
  #pragma unroll
  for (int o=32;o>0;o>>=1) v = fmaxf(v, __shfl_xor(v,o));
  return v;
}
__device__ float blockRedSum(float v){
  __shared__ float tmp[17];
  const int lane = threadIdx.x&63, wv = threadIdx.x>>6, nw = blockDim.x>>6;
  v = waveRedSum(v);
  __syncthreads();
  if (lane==0) tmp[wv]=v;
  __syncthreads();
  if (threadIdx.x==0){ float s=tmp[0]; for(int i=1;i<nw;i++) s+=tmp[i]; tmp[16]=s; }
  __syncthreads();
  return tmp[16];
}
__device__ float blockRedMax(float v){
  __shared__ float tmp[17];
  const int lane = threadIdx.x&63, wv = threadIdx.x>>6, nw = blockDim.x>>6;
  v = waveRedMax(v);
  __syncthreads();
  if (lane==0) tmp[wv]=v;
  __syncthreads();
  if (threadIdx.x==0){ float s=tmp[0]; for(int i=1;i<nw;i++) s=fmaxf(s,tmp[i]); tmp[16]=s; }
  __syncthreads();
  return tmp[16];
}

// ============================================================================
// Plain bf16 NT GEMM (stage F).
// C[m][n] = sum_k A[m][k]*B[n][k]; batch z -> zb=z/H, zh=z%H.
enum { EPI_NONE=0, EPI_BIAS=1, EPI_SCALE=3, EPI_VT=5 };

template<int EPI>
__global__ __launch_bounds__(256,2)
void gemm_nt(const u16* __restrict__ Ag, long long lda, long long sA1, long long sA2,
             const u16* __restrict__ Bg, long long ldb, long long sB1, long long sB2,
             u16* __restrict__ Cg, long long ldc, long long sC1, long long sC2,
             const float* __restrict__ bias, long long sBias,
             float scale, int K, int H)
{
  __shared__ u16 As[128*32];
  __shared__ u16 Bs[128*32];
  const int z  = blockIdx.z;
  const int zb = z / H, zh = z - zb*H;
  const u16* A = Ag + zb*sA1 + zh*sA2;
  const u16* B = Bg + zb*sB1 + zh*sB2;
  const int m0 = blockIdx.y*128, n0 = blockIdx.x*128;
  const int t  = threadIdx.x;
  const int lane = t & 63, wv = t >> 6;
  const int wm = (wv>>1)*64, wn = (wv&1)*64;

  const u16* ga0 = A + (long long)(m0 + (t>>2))*lda + (t&3)*8;
  const u16* ga1 = ga0 + 64*lda;
  const u16* gb0 = B + (long long)(n0 + (t>>2))*ldb + (t&3)*8;
  const u16* gb1 = gb0 + 64*ldb;
  uint4* sA = (uint4*)As;
  uint4* sB = (uint4*)Bs;

  f32x4 acc[4][4];
  #pragma unroll
  for (int i=0;i<4;i++)
    #pragma unroll
    for (int j=0;j<4;j++) acc[i][j] = (f32x4){0.f,0.f,0.f,0.f};

  const short8* arp = (const short8*)(As + (wm + (lane&15))*32 + ((lane>>4)*8));
  const short8* brp = (const short8*)(Bs + (wn + (lane&15))*32 + ((lane>>4)*8));

  for (int kk = 0; kk < K; kk += 32) {
    const uint4 a0 = *(const uint4*)ga0;
    const uint4 a1 = *(const uint4*)ga1;
    const uint4 b0 = *(const uint4*)gb0;
    const uint4 b1 = *(const uint4*)gb1;
    ga0 += 32; ga1 += 32; gb0 += 32; gb1 += 32;
    __syncthreads();
    sA[t] = a0; sA[256+t] = a1;
    sB[t] = b0; sB[256+t] = b1;
    __syncthreads();
    short8 af[4], bfr[4];
    #pragma unroll
    for (int i=0;i<4;i++) af[i]  = arp[i*64];
    #pragma unroll
    for (int j=0;j<4;j++) bfr[j] = brp[j*64];
    #pragma unroll
    for (int i=0;i<4;i++)
      #pragma unroll
      for (int j=0;j<4;j++)
        acc[i][j] = __builtin_amdgcn_mfma_f32_16x16x32_bf16(af[i], bfr[j], acc[i][j], 0, 0, 0);
  }

  u16* C = Cg + zb*sC1 + zh*sC2;
  const float* bz = bias + zb*sBias;
  const int rb0 = m0 + wm + ((lane>>4)<<2);
  const int cb0 = n0 + wn + (lane&15);
  #pragma unroll
  for (int j=0;j<4;j++){
    const int cn = cb0 + j*16;
    float bv = 0.f;
    if constexpr (EPI==EPI_BIAS || EPI==EPI_VT) bv = bz[cn];
    #pragma unroll
    for (int i=0;i<4;i++){
      #pragma unroll
      for (int p=0;p<4;p++){
        const int row = rb0 + i*16 + p;
        float v = acc[i][j][p];
        if constexpr (EPI==EPI_SCALE) v *= scale;
        if constexpr (EPI==EPI_BIAS)  v += bv;
        if constexpr (EPI==EPI_VT) {
          v += bv;
          const int bb = row>>8, tt = row&255, hh = cn>>7, dd = cn&127;
          C[((long long)((bb*8+hh)*128+dd)<<8) + tt] = f2b(v);
        } else {
          C[(long long)row*ldc + cn] = f2b(v);
        }
      }
    }
  }
}

// ============================================================================
// Split-bf16 NT GEMM: A ~ Ah+Al, B ~ Bh+Bl; acc += Al*Bh + Ah*Bl + Ah*Bh.
enum { SP_GELU_SPLIT=0, SP_BIAS_SPLIT=1, SP_SCALE_F32=2, SP_QBG_F32=3 };

template<int EPI>
__global__ __launch_bounds__(256,2)
void gemm_nt_split(const u16* __restrict__ Ah_, const u16* __restrict__ Al_, long long lda,
                   const u16* __restrict__ Bh_, const u16* __restrict__ Bl_, long long ldb,
                   void* __restrict__ C0, void* __restrict__ C1, long long ldc,
                   const float* __restrict__ bias, float scale, int K)
{
  __shared__ u16 AsH[128*32];
  __shared__ u16 AsL[128*32];
  __shared__ u16 BsH[128*32];
  __shared__ u16 BsL[128*32];
  const int m0 = blockIdx.y*128, n0 = blockIdx.x*128;
  const int t  = threadIdx.x;
  const int lane = t & 63, wv = t >> 6;
  const int wm = (wv>>1)*64, wn = (wv&1)*64;

  const long long arow = (long long)(m0 + (t>>2))*lda + (t&3)*8;
  const long long brow = (long long)(n0 + (t>>2))*ldb + (t&3)*8;
  const u16* gah0 = Ah_ + arow;  const u16* gah1 = gah0 + 64*lda;
  const u16* gal0 = Al_ + arow;  const u16* gal1 = gal0 + 64*lda;
  const u16* gbh0 = Bh_ + brow;  const u16* gbh1 = gbh0 + 64*ldb;
  const u16* gbl0 = Bl_ + brow;  const u16* gbl1 = gbl0 + 64*ldb;
  uint4* sAH = (uint4*)AsH;  uint4* sAL = (uint4*)AsL;
  uint4* sBH = (uint4*)BsH;  uint4* sBL = (uint4*)BsL;

  f32x4 acc[4][4];
  #pragma unroll
  for (int i=0;i<4;i++)
    #pragma unroll
    for (int j=0;j<4;j++) acc[i][j] = (f32x4){0.f,0.f,0.f,0.f};

  const int foff = (lane&15)*32 + ((lane>>4)*8);
  const short8* arh = (const short8*)(AsH + wm*32 + foff);
  const short8* arl = (const short8*)(AsL + wm*32 + foff);
  const short8* brh = (const short8*)(BsH + wn*32 + foff);
  const short8* brl = (const short8*)(BsL + wn*32 + foff);

  for (int kk = 0; kk < K; kk += 32) {
    const uint4 ah0 = *(const uint4*)gah0;  const uint4 ah1 = *(const uint4*)gah1;
    const uint4 al0 = *(const uint4*)gal0;  const uint4 al1 = *(const uint4*)gal1;
    const uint4 bh0 = *(const uint4*)gbh0;  const uint4 bh1 = *(const uint4*)gbh1;
    const uint4 bl0 = *(const uint4*)gbl0;  const uint4 bl1 = *(const uint4*)gbl1;
    gah0 += 32; gah1 += 32; gal0 += 32; gal1 += 32;
    gbh0 += 32; gbh1 += 32; gbl0 += 32; gbl1 += 32;
    __syncthreads();
    sAH[t] = ah0; sAH[256+t] = ah1;
    sAL[t] = al0; sAL[256+t] = al1;
    sBH[t] = bh0; sBH[256+t] = bh1;
    sBL[t] = bl0; sBL[256+t] = bl1;
    __syncthreads();
    short8 fah[4], fal[4], fbh[4], fbl[4];
    #pragma unroll
    for (int i=0;i<4;i++){ fah[i]=arh[i*64]; fal[i]=arl[i*64]; }
    #pragma unroll
    for (int j=0;j<4;j++){ fbh[j]=brh[j*64]; fbl[j]=brl[j*64]; }
    #pragma unroll
    for (int i=0;i<4;i++)
      #pragma unroll
      for (int j=0;j<4;j++){
        acc[i][j] = __builtin_amdgcn_mfma_f32_16x16x32_bf16(fal[i], fbh[j], acc[i][j], 0, 0, 0);
        acc[i][j] = __builtin_amdgcn_mfma_f32_16x16x32_bf16(fah[i], fbl[j], acc[i][j], 0, 0, 0);
        acc[i][j] = __builtin_amdgcn_mfma_f32_16x16x32_bf16(fah[i], fbh[j], acc[i][j], 0, 0, 0);
      }
  }

  const int rb0 = m0 + wm + ((lane>>4)<<2);
  const int cb0 = n0 + wn + (lane&15);
  #pragma unroll
  for (int j=0;j<4;j++){
    const int cn = cb0 + j*16;
    float bv = 0.f;
    if constexpr (EPI==SP_GELU_SPLIT || EPI==SP_BIAS_SPLIT) bv = bias[cn];
    #pragma unroll
    for (int i=0;i<4;i++){
      #pragma unroll
      for (int p=0;p<4;p++){
        const int row = rb0 + i*16 + p;
        float v = acc[i][j][p];
        const long long o = (long long)row*ldc + cn;
        if constexpr (EPI==SP_GELU_SPLIT || EPI==SP_BIAS_SPLIT){
          v += bv;
          if constexpr (EPI==SP_GELU_SPLIT) v = gelu_f(v);
          const u16 h = f2b(v);
          ((u16*)C0)[o] = h;
          ((u16*)C1)[o] = f2b(v - b2f(h));
        }
        if constexpr (EPI==SP_SCALE_F32) ((float*)C0)[o] = v*scale;
        if constexpr (EPI==SP_QBG_F32)   ((float*)C0)[o] = gelu_f(v + bias[(row>>8)*512 + cn]);
      }
    }
  }
}

// ---------------- prep kernels ----------------
__global__ void transpose_w(const float* __restrict__ in, u16* __restrict__ out, int rows, int cols){
  __shared__ float tl[32][33];
  const long long zo = (long long)blockIdx.z*rows*cols;
  const int c0 = blockIdx.x*32, r0 = blockIdx.y*32;
  const int tx = threadIdx.x, ty = threadIdx.y;
  #pragma unroll
  for (int yy=ty; yy<32; yy+=8) tl[yy][tx] = in[zo + (long long)(r0+yy)*cols + (c0+tx)];
  __syncthreads();
  #pragma unroll
  for (int yy=ty; yy<32; yy+=8) out[zo + (long long)(c0+yy)*rows + (r0+tx)] = f2b(tl[tx][yy]);
}

__global__ void split_transpose_w(const float* __restrict__ in, u16* __restrict__ outH,
                                  u16* __restrict__ outL, int rows, int cols){
  __shared__ float tl[32][33];
  const long long zo = (long long)blockIdx.z*rows*cols;
  const int c0 = blockIdx.x*32, r0 = blockIdx.y*32;
  const int tx = threadIdx.x, ty = threadIdx.y;
  #pragma unroll
  for (int yy=ty; yy<32; yy+=8) tl[yy][tx] = in[zo + (long long)(r0+yy)*cols + (c0+tx)];
  __syncthreads();
  #pragma unroll
  for (int yy=ty; yy<32; yy+=8){
    const float v = tl[tx][yy];
    const u16 h = f2b(v);
    const long long o = zo + (long long)(c0+yy)*rows + (r0+tx);
    outH[o] = h;
    outL[o] = f2b(v - b2f(h));
  }
}

__global__ void split_f32_k(const float* __restrict__ in, u16* __restrict__ oh,
                            u16* __restrict__ ol, int n4){
  const int i = blockIdx.x*256 + threadIdx.x;
  if (i < n4){
    const float4 v = ((const float4*)in)[i];
    u16x4 hh, ll;
    hh.x=f2b(v.x); ll.x=f2b(v.x-b2f(hh.x));
    hh.y=f2b(v.y); ll.y=f2b(v.y-b2f(hh.y));
    hh.z=f2b(v.z); ll.z=f2b(v.z-b2f(hh.z));
    hh.w=f2b(v.w); ll.w=f2b(v.w-b2f(hh.w));
    ((u16x4*)oh)[i] = hh;
    ((u16x4*)ol)[i] = ll;
  }
}

__global__ void zero_f32(float* __restrict__ p, int n){
  const int i = blockIdx.x*256 + threadIdx.x;
  if (i < n) p[i] = 0.f;
}

__global__ void ws_report(float* __restrict__ out, int n4, float val){
  const int i = blockIdx.x*256 + threadIdx.x;
  if (i < n4){
    float4 z; z.x = (i==0)? val : 0.f; z.y=0.f; z.z=0.f; z.w=0.f;
    ((float4*)out)[i] = z;
  }
}

// ---------------- pooling (fp32 scores) ----------------
__global__ void row_stats_f32(const float* __restrict__ S, float* __restrict__ mOut,
                              float* __restrict__ dOut){
  const int row = blockIdx.x;
  const float4* p = (const float4*)(S + (long long)row*2048);
  const int tid = threadIdx.x;
  const float4 a = p[2*tid], b = p[2*tid+1];
  float v[8] = {a.x,a.y,a.z,a.w,b.x,b.y,b.z,b.w};
  float mx = v[0];
  #pragma unroll
  for (int k=1;k<8;k++) mx = fmaxf(mx, v[k]);
  mx = blockRedMax(mx);
  float s = 0.f;
  #pragma unroll
  for (int k=0;k<8;k++) s += expf(v[k]-mx);
  s = blockRedSum(s);
  if (tid==0){ mOut[row]=mx; dOut[row]=s; }
}

__global__ void col_mean_f32(const float* __restrict__ S, const float* __restrict__ m,
                             const float* __restrict__ den, float* __restrict__ w){
  const int tc = blockIdx.x*256 + threadIdx.x;
  const int s0 = blockIdx.y*256;
  const float* p = S + (long long)s0*2048 + tc;
  float acc = 0.f;
  for (int s=0;s<256;s++)
    acc += expf(p[(long long)s<<11] - m[s0+s]) * (1.0f/den[s0+s]);
  atomicAdd(&w[tc], acc * (1.f/2048.f));
}

// pooled[b][d] = sum_t w[b][t]*(qfh+qfl)[b][t][d]
__global__ __launch_bounds__(1024)
void pooled_gemv(const u16* __restrict__ qfh, const u16* __restrict__ qfl,
                 const float* __restrict__ w, float* __restrict__ pooled){
  const int b = blockIdx.x, d = threadIdx.x;
  __shared__ float wsh[2048];
  wsh[d] = w[b*2048+d]; wsh[1024+d] = w[b*2048+1024+d];
  __syncthreads();
  const u16* ph = qfh + (long long)b*2097152 + d;
  const u16* pl = qfl + (long long)b*2097152 + d;
  float acc = 0.f;
  for (int t=0; t<2048; t++){
    const long long o = (long long)t<<10;
    acc += wsh[t]*(b2f(ph[o]) + b2f(pl[o]));
  }
  pooled[b*1024+d] = acc;
}

// LN(pooled) @ pool_w + pool_b -> queries (fp32)
__global__ __launch_bounds__(1024)
void ln_query(const float* __restrict__ pooled, const float* __restrict__ pg,
              const float* __restrict__ pb, const float* __restrict__ pw,
              const float* __restrict__ pbias, float* __restrict__ queries){
  const int z = blockIdx.x, r = z>>2, d = threadIdx.x;
  __shared__ float pl[1024];
  const float v = pooled[z*1024+d];
  const float mean = blockRedSum(v) * (1.f/1024.f);
  const float df = v - mean;
  const float var = blockRedSum(df*df) * (1.f/1024.f);
  pl[d] = df*rsqrtf(var+1e-5f)*pg[r*1024+d] + pb[r*1024+d];
  __syncthreads();
  float qa = pbias[r*1024+d];
  const float* pwp = pw + (long long)r*1048576 + d;
  for (int k=0;k<1024;k++) qa += pl[k]*pwp[(long long)k<<10];
  queries[z*1024+d] = qa;
}

// qpart[z][n] = queries[z] @ rel_w1[1024:,:] + rel_b1  (fp32)
__global__ __launch_bounds__(512)
void qpart_gemv(const float* __restrict__ queries, const float* __restrict__ rw1,
                const float* __restrict__ rb1, float* __restrict__ qpart){
  const int z = blockIdx.x, n = threadIdx.x;
  float a = rb1[n];
  const float* q = queries + z*1024;
  const float* w = rw1 + 1024*512 + n;
  for (int d=0;d<1024;d++) a += q[d]*w[(long long)d*512];
  qpart[z*512+n] = a;
}

// rel = sigmoid(h @ rel_w2 + rel_b2), h fp32; one wave per row
__global__ void rel_score_f32(const float* __restrict__ h, const float* __restrict__ w2,
                              const float* __restrict__ b2p, float* __restrict__ relv){
  const int row = blockIdx.x*4 + (threadIdx.x>>6);
  const int lane = threadIdx.x & 63;
  const float* p = h + (long long)row*512;
  float a = 0.f;
  #pragma unroll
  for (int k=0;k<8;k++){ const int idx = lane + k*64; a += p[idx]*w2[idx]; }
  a = waveRedSum(a);
  if (lane==0){
    const float lg = a + b2p[0];
    relv[row] = 1.f/(1.f+expf(-lg));
  }
}

// ---------------- selection ----------------
__global__ __launch_bounds__(768)
void select_topk(const float* __restrict__ relv, int* __restrict__ selidx,
                 int* __restrict__ neff, int* __restrict__ anyv){
  const int b = blockIdx.x, c = threadIdx.x;
  __shared__ float rv[768];
  __shared__ int cnt;
  rv[c] = relv[(((c>>8)*4)+b)*256 + (c&255)];
  if (c==0) cnt = 0;
  __syncthreads();
  const float mine = rv[c];
  const bool valid = (mine >= 0.5f);
  int rank = 0;
  for (int j=0;j<768;j++){
    const float vj = rv[j];
    if (vj >= 0.5f && (vj > mine || (vj == mine && j < c))) rank++;
  }
  if (valid && rank < 256){
    const int s = atomicAdd(&cnt, 1);
    selidx[b*256 + s] = c;
  }
  __syncthreads();
  if (c==0){ neff[b] = cnt; anyv[b] = (cnt>0) ? 1 : 0; }
}

__global__ void gather_sel(const u16* __restrict__ rb16, const int* __restrict__ selidx,
                           const int* __restrict__ neff, u16* __restrict__ seltok){
  const int slot = blockIdx.x, b = blockIdx.y, tid = threadIdx.x;
  uint2 val; val.x=0u; val.y=0u;
  if (slot < neff[b]){
    const int c = selidx[b*256+slot];
    const uint2* src = (const uint2*)(rb16 + (long long)(((c>>8)*4+b)*256 + (c&255))*1024);
    val = src[tid];
  }
  ((uint2*)(seltok + (long long)(b*256+slot)*1024))[tid] = val;
}

// masked softmax over key slots (one wave per row of 256)
__global__ void attn_softmax(u16* __restrict__ S, const int* __restrict__ neff){
  const int ri = blockIdx.x*4 + (threadIdx.x>>6);
  const int lane = threadIdx.x & 63;
  const int b = ri >> 14;
  const int ne = neff[b];
  u16* p = S + (long long)ri*256 + lane*4;
  if (ne == 0){ uint2 zz; zz.x=0u; zz.y=0u; *(uint2*)p = zz; return; }
  uint2 raw = *(const uint2*)p;
  u16 uu[4] = {(u16)(raw.x&0xffffu),(u16)(raw.x>>16),(u16)(raw.y&0xffffu),(u16)(raw.y>>16)};
  float xs[4];
  #pragma unroll
  for (int q2=0;q2<4;q2++){ const int tt = lane*4+q2; xs[q2] = (tt<ne)? b2f(uu[q2]) : -1e30f; }
  float mx = fmaxf(fmaxf(xs[0],xs[1]),fmaxf(xs[2],xs[3]));
  mx = waveRedMax(mx);
  float e[4]; float sm=0.f;
  #pragma unroll
  for (int q2=0;q2<4;q2++){ e[q2] = (lane*4+q2<ne)? expf(xs[q2]-mx) : 0.f; sm += e[q2]; }
  sm = waveRedSum(sm);
  const float inv = 1.f/sm;
  #pragma unroll
  for (int q2=0;q2<4;q2++) uu[q2] = f2b(e[q2]*inv);
  raw.x = (u32)uu[0] | ((u32)uu[1]<<16);
  raw.y = (u32)uu[2] | ((u32)uu[3]<<16);
  *(uint2*)p = raw;
}

// residual + LayerNorm + any_valid select
__global__ void final_ln(const float* __restrict__ x, const u16* __restrict__ fused,
                         const float* __restrict__ g, const float* __restrict__ bb,
                         const int* __restrict__ anyv, float* __restrict__ out){
  const int row = blockIdx.x; const int b = row>>11; const int tid = threadIdx.x;
  const float4 xv = ((const float4*)(x + (long long)row*1024))[tid];
  const uint2 fv = ((const uint2*)(fused + (long long)row*1024))[tid];
  const float e0 = xv.x + b2f((u16)(fv.x&0xffffu));
  const float e1 = xv.y + b2f((u16)(fv.x>>16));
  const float e2 = xv.z + b2f((u16)(fv.y&0xffffu));
  const float e3 = xv.w + b2f((u16)(fv.y>>16));
  const float mean = blockRedSum(e0+e1+e2+e3) * (1.f/1024.f);
  const float d0=e0-mean, d1=e1-mean, d2=e2-mean, d3=e3-mean;
  const float var = blockRedSum(d0*d0+d1*d1+d2*d2+d3*d3) * (1.f/1024.f);
  const float inv = rsqrtf(var + 1e-5f);
  const float4 gv = ((const float4*)g)[tid];
  const float4 bv = ((const float4*)bb)[tid];
  float4 o;
  if (anyv[b]){
    o.x = d0*inv*gv.x + bv.x; o.y = d1*inv*gv.y + bv.y;
    o.z = d2*inv*gv.z + bv.z; o.w = d3*inv*gv.w + bv.w;
  } else o = xv;
  ((float4*)(out + (long long)row*1024))[tid] = o;
}

// ============================================================================
extern "C" void kernel_launch(void* const* d_in, const int* in_sizes, int n_in,
                              void* d_out, int out_size, void* d_ws, size_t ws_size,
                              hipStream_t stream) {
  (void)in_sizes; (void)n_in;
  const float* x      = (const float*)d_in[0];
  const float* retr   = (const float*)d_in[1];
  const float* qg_w1  = (const float*)d_in[2];
  const float* qg_b1  = (const float*)d_in[3];
  const float* qg_w2  = (const float*)d_in[4];
  const float* qg_b2  = (const float*)d_in[5];
  const float* pln_g  = (const float*)d_in[6];
  const float* pln_b  = (const float*)d_in[7];
  const float* pool_w = (const float*)d_in[8];
  const float* pool_b = (const float*)d_in[9];
  const float* rel_w1 = (const float*)d_in[10];
  const float* rel_b1 = (const float*)d_in[11];
  const float* rel_w2 = (const float*)d_in[12];
  const float* rel_b2 = (const float*)d_in[13];
  const float* in_w   = (const float*)d_in[14];
  const float* in_b   = (const float*)d_in[15];
  const float* out_w  = (const float*)d_in[16];
  const float* out_b  = (const float*)d_in[17];
  const float* fln_g  = (const float*)d_in[18];
  const float* fln_b  = (const float*)d_in[19];
  float* out = (float*)d_out;
  char* ws = (char*)d_ws;

  const size_t MB = 1u<<20;
  const size_t REQUIRED = 131*MB;
  if (ws_size < REQUIRED){
    ws_report<<<(out_size/4 + 255)/256, 256, 0, stream>>>(out, out_size/4, (float)(ws_size>>20));
    return;
  }

  // ---- layout (MB offsets; lifetimes commented) ----
  u16* qg1Th = (u16*)(ws + 0*MB);    // 6   [A]
  u16* qg1Tl = (u16*)(ws + 6*MB);    // 6   [A]
  u16* qg2Th = (u16*)(ws + 12*MB);   // 6   [A]
  u16* qg2Tl = (u16*)(ws + 18*MB);   // 6   [A]
  u16* xh    = (u16*)(ws + 24*MB);   // 16  [A, F]  (= bf16(x))
  u16* xl    = (u16*)(ws + 40*MB);   // 16  [A]
  u16* rh    = (u16*)(ws + 56*MB);   // 6   [D, E]  (= bf16(retr))
  u16* rl    = (u16*)(ws + 62*MB);   // 6   [D]
  u16* relTh = (u16*)(ws + 68*MB);   // 1   [D]
  u16* relTl = (u16*)(ws + 69*MB);   // 1   [D]
  u16* qfh   = (u16*)(ws + 70*MB);   // 16  [A->B] per retriever
  u16* qfl   = (u16*)(ws + 86*MB);   // 16  [A->B]
  // region 102..118: t1h/t1l (A, per half) | scores fp32 (B, per batch) | hbuf (D) | attnout (F)
  u16*   t1h    = (u16*)(ws + 102*MB);  // 8
  u16*   t1l    = (u16*)(ws + 110*MB);  // 8
  float* scores = (float*)(ws + 102*MB);// 16
  float* hbuf   = (float*)(ws + 102*MB);// 6
  u16*   attnout= (u16*)(ws + 102*MB);  // 16
  // stage F reuse of dead zones (each 2 MB now — R3 bug was 1 MB slots):
  u16* qbuf   = (u16*)(ws + 0*MB);    // 16 (over qg1T/qg2T, dead after A)
  u16* fused  = (u16*)(ws + 0*MB);    // 16 (over qbuf, dead after QK^T)
  u16* inT    = (u16*)(ws + 40*MB);   // 6  (over xl, dead after A)
  u16* outT   = (u16*)(ws + 46*MB);   // 2
  u16* seltok = (u16*)(ws + 48*MB);   // 2  [4][256][1024] bf16
  u16* kbuf   = (u16*)(ws + 50*MB);   // 2
  u16* VT     = (u16*)(ws + 52*MB);   // 2  (54..56 spare)
  u16* Sattn  = (u16*)(ws + 70*MB);   // 32 (over qfh/qfl, dead after pooling)
  // smalls at 118..
  char* SM = ws + 118*MB;
  float* wbuf    = (float*)(SM);            // 96 KB [12][2048]
  float* pooledB = (float*)(SM + 98304);    // 48 KB [12][1024]
  float* queries = (float*)(SM + 147456);   // 48 KB
  float* qpart   = (float*)(SM + 196608);   // 24 KB
  float* relv    = (float*)(SM + 221184);   // 12 KB
  int*   selidx  = (int*)(SM + 233472);     //  4 KB
  int*   neff    = (int*)(SM + 237568);
  int*   anyv    = (int*)(SM + 237632);
  float* mrow    = (float*)(SM + 237696);   //  8 KB [2048]
  float* drow    = (float*)(SM + 245888);   //  8 KB

  dim3 b256(256);
  dim3 tb(32,8);

  // --- prep: split weights/activations ---
  split_transpose_w<<<dim3(32,32,3), tb, 0, stream>>>(qg_w1, qg1Th, qg1Tl, 1024, 1024);
  split_transpose_w<<<dim3(32,32,3), tb, 0, stream>>>(qg_w2, qg2Th, qg2Tl, 1024, 1024);
  split_transpose_w<<<dim3(16,32,1), tb, 0, stream>>>(rel_w1, relTh, relTl, 1024, 512);
  split_f32_k<<<8192, b256, 0, stream>>>(x,    xh, xl, 2097152);
  split_f32_k<<<3072, b256, 0, stream>>>(retr, rh, rl,  786432);
  zero_f32<<<96, b256, 0, stream>>>(wbuf, 24576);

  // --- stages A+B per retriever (split precision) ---
  for (int r = 0; r < 3; r++){
    const long long wo = (long long)r*1048576;
    for (int hf = 0; hf < 2; hf++){
      const long long xo = (long long)hf*4194304;   // 4096 rows * 1024
      gemm_nt_split<SP_GELU_SPLIT><<<dim3(8,32), b256, 0, stream>>>(
          xh+xo, xl+xo, 1024,  qg1Th+wo, qg1Tl+wo, 1024,
          t1h, t1l, 1024,  qg_b1+r*1024, 1.f, 1024);
      gemm_nt_split<SP_BIAS_SPLIT><<<dim3(8,32), b256, 0, stream>>>(
          t1h, t1l, 1024,  qg2Th+wo, qg2Tl+wo, 1024,
          qfh+xo, qfl+xo, 1024,  qg_b2+r*1024, 1.f, 1024);
    }
    for (int b = 0; b < 4; b++){
      const long long qo = (long long)b*2097152;
      gemm_nt_split<SP_SCALE_F32><<<dim3(16,16), b256, 0, stream>>>(
          qfh+qo, qfl+qo, 1024,  qfh+qo, qfl+qo, 1024,
          scores, nullptr, 2048,  nullptr, 0.03125f, 1024);
      row_stats_f32<<<2048, b256, 0, stream>>>(scores, mrow, drow);
      col_mean_f32<<<dim3(8,8), b256, 0, stream>>>(scores, mrow, drow, wbuf + (r*4+b)*2048);
    }
    pooled_gemv<<<4, 1024, 0, stream>>>(qfh, qfl, wbuf + r*8192, pooledB + r*4096);
  }
  ln_query<<<12, 1024, 0, stream>>>(pooledB, pln_g, pln_b, pool_w, pool_b, queries);

  // --- stage D: relevance scorer (split GEMM, fp32 h) ---
  qpart_gemv<<<12, 512, 0, stream>>>(queries, rel_w1, rel_b1, qpart);
  gemm_nt_split<SP_QBG_F32><<<dim3(4,24), b256, 0, stream>>>(
      rh, rl, 1024,  relTh, relTl, 1024,  hbuf, nullptr, 512,  qpart, 1.f, 1024);
  rel_score_f32<<<768, b256, 0, stream>>>(hbuf, rel_w2, rel_b2, relv);

  // --- stage E: selection ---
  select_topk<<<4, 768, 0, stream>>>(relv, selidx, neff, anyv);
  gather_sel<<<dim3(256,4), b256, 0, stream>>>(rh, selidx, neff, seltok);

  // --- stage F: fusion cross-attention (plain bf16) ---
  transpose_w<<<dim3(32,32,3), tb, 0, stream>>>(in_w,  inT,  1024, 1024);
  transpose_w<<<dim3(32,32,1), tb, 0, stream>>>(out_w, outT, 1024, 1024);
  gemm_nt<EPI_BIAS><<<dim3(8,64,1), b256, 0, stream>>>(
      xh,1024,0,0,  inT,1024,0,0,  qbuf,1024,0,0,  in_b,0, 1.f, 1024, 1);
  gemm_nt<EPI_BIAS><<<dim3(8,8,1), b256, 0, stream>>>(
      seltok,1024,0,0,  inT+1048576,1024,0,0,  kbuf,1024,0,0,  in_b+1024,0, 1.f, 1024, 1);
  gemm_nt<EPI_VT><<<dim3(8,8,1), b256, 0, stream>>>(
      seltok,1024,0,0,  inT+2097152,1024,0,0,  VT,0,0,0,  in_b+2048,0, 1.f, 1024, 1);
  gemm_nt<EPI_SCALE><<<dim3(2,16,32), b256, 0, stream>>>(
      qbuf,1024,2097152,128,  kbuf,1024,262144,128,  Sattn,256,4194304,524288,
      (const float*)nullptr,0, 0.08838834764831845f, 128, 8);
  attn_softmax<<<16384, b256, 0, stream>>>(Sattn, neff);
  gemm_nt<EPI_NONE><<<dim3(1,16,32), b256, 0, stream>>>(
      Sattn,256,4194304,524288,  VT,256,262144,32768,  attnout,1024,2097152,128,
      (const float*)nullptr,0, 1.f, 256, 8);
  gemm_nt<EPI_BIAS><<<dim3(8,64,1), b256, 0, stream>>>(
      attnout,1024,0,0,  outT,1024,0,0,  fused,1024,0,0,  out_b,0, 1.f, 1024, 1);
  final_ln<<<8192, b256, 0, stream>>>(x, fused, fln_g, fln_b, anyv, out);
}

// Round 5
// 2579.707 us; speedup vs baseline: 1.0290x; 1.0290x over previous
//
#include <hip/hip_runtime.h>
#include <math.h>

// ============================================================================
// RetrievalAugmentedProcessor — MI355X (gfx950)
// B=4 S=2048 D=1024 R=3 K=256 MAXR=256 H=8 HD=128
// R5: parallelize the latency-bound small-GEMV tail exposed by rocprof:
//     pooled_gemv (4 blocks, 181us x3 = 544us, 0.7% occupancy) -> pooled_par
//     (64 blocks/retriever, coalesced, atomicAdd). ln_query -> pool_ln +
//     query_gemv (96 blocks). qpart_gemv -> qpart_par (48 blocks).
//     GEMM cores unchanged from R4 (green, absmax 0.031).
// ============================================================================

typedef unsigned short u16;
typedef unsigned int   u32;
typedef __attribute__((ext_vector_type(8))) short short8;   // 8 bf16
typedef __attribute__((ext_vector_type(4))) float f32x4;    // MFMA acc
typedef __attribute__((ext_vector_type(4))) u16  u16x4;

__device__ __forceinline__ float b2f(u16 u){ union{float f;u32 i;} x; x.i=((u32)u)<<16; return x.f; }
__device__ __forceinline__ u16 f2b(float f){ union{float f;u32 i;} x; x.f=f; u32 r=x.i+0x7fffu+((x.i>>16)&1u); return (u16)(r>>16); }
__device__ __forceinline__ float gelu_f(float v){ return 0.5f*v*(1.f+erff(v*0.70710678118654752f)); }

// ---------------- reductions ----------------
__device__ __forceinline__ float waveRedSum(float v){
  #pragma unroll
  for (int o=32;o>0;o>>=1) v += __shfl_xor(v,o);
  return v;
}
__device__ __forceinline__ float waveRedMax(float v){
  #pragma unroll
  for (int o=32;o>0;o>>=1) v = fmaxf(v, __shfl_xor(v,o));
  return v;
}
__device__ float blockRedSum(float v){
  __shared__ float tmp[17];
  const int lane = threadIdx.x&63, wv = threadIdx.x>>6, nw = blockDim.x>>6;
  v = waveRedSum(v);
  __syncthreads();
  if (lane==0) tmp[wv]=v;
  __syncthreads();
  if (threadIdx.x==0){ float s=tmp[0]; for(int i=1;i<nw;i++) s+=tmp[i]; tmp[16]=s; }
  __syncthreads();
  return tmp[16];
}
__device__ float blockRedMax(float v){
  __shared__ float tmp[17];
  const int lane = threadIdx.x&63, wv = threadIdx.x>>6, nw = blockDim.x>>6;
  v = waveRedMax(v);
  __syncthreads();
  if (lane==0) tmp[wv]=v;
  __syncthreads();
  if (threadIdx.x==0){ float s=tmp[0]; for(int i=1;i<nw;i++) s=fmaxf(s,tmp[i]); tmp[16]=s; }
  __syncthreads();
  return tmp[16];
}

// ============================================================================
// Plain bf16 NT GEMM (stage F).
enum { EPI_NONE=0, EPI_BIAS=1, EPI_SCALE=3, EPI_VT=5 };

template<int EPI>
__global__ __launch_bounds__(256,2)
void gemm_nt(const u16* __restrict__ Ag, long long lda, long long sA1, long long sA2,
             const u16* __restrict__ Bg, long long ldb, long long sB1, long long sB2,
             u16* __restrict__ Cg, long long ldc, long long sC1, long long sC2,
             const float* __restrict__ bias, long long sBias,
             float scale, int K, int H)
{
  __shared__ u16 As[128*32];
  __shared__ u16 Bs[128*32];
  const int z  = blockIdx.z;
  const int zb = z / H, zh = z - zb*H;
  const u16* A = Ag + zb*sA1 + zh*sA2;
  const u16* B = Bg + zb*sB1 + zh*sB2;
  const int m0 = blockIdx.y*128, n0 = blockIdx.x*128;
  const int t  = threadIdx.x;
  const int lane = t & 63, wv = t >> 6;
  const int wm = (wv>>1)*64, wn = (wv&1)*64;

  const u16* ga0 = A + (long long)(m0 + (t>>2))*lda + (t&3)*8;
  const u16* ga1 = ga0 + 64*lda;
  const u16* gb0 = B + (long long)(n0 + (t>>2))*ldb + (t&3)*8;
  const u16* gb1 = gb0 + 64*ldb;
  uint4* sA = (uint4*)As;
  uint4* sB = (uint4*)Bs;

  f32x4 acc[4][4];
  #pragma unroll
  for (int i=0;i<4;i++)
    #pragma unroll
    for (int j=0;j<4;j++) acc[i][j] = (f32x4){0.f,0.f,0.f,0.f};

  const short8* arp = (const short8*)(As + (wm + (lane&15))*32 + ((lane>>4)*8));
  const short8* brp = (const short8*)(Bs + (wn + (lane&15))*32 + ((lane>>4)*8));

  for (int kk = 0; kk < K; kk += 32) {
    const uint4 a0 = *(const uint4*)ga0;
    const uint4 a1 = *(const uint4*)ga1;
    const uint4 b0 = *(const uint4*)gb0;
    const uint4 b1 = *(const uint4*)gb1;
    ga0 += 32; ga1 += 32; gb0 += 32; gb1 += 32;
    __syncthreads();
    sA[t] = a0; sA[256+t] = a1;
    sB[t] = b0; sB[256+t] = b1;
    __syncthreads();
    short8 af[4], bfr[4];
    #pragma unroll
    for (int i=0;i<4;i++) af[i]  = arp[i*64];
    #pragma unroll
    for (int j=0;j<4;j++) bfr[j] = brp[j*64];
    #pragma unroll
    for (int i=0;i<4;i++)
      #pragma unroll
      for (int j=0;j<4;j++)
        acc[i][j] = __builtin_amdgcn_mfma_f32_16x16x32_bf16(af[i], bfr[j], acc[i][j], 0, 0, 0);
  }

  u16* C = Cg + zb*sC1 + zh*sC2;
  const float* bz = bias + zb*sBias;
  const int rb0 = m0 + wm + ((lane>>4)<<2);
  const int cb0 = n0 + wn + (lane&15);
  #pragma unroll
  for (int j=0;j<4;j++){
    const int cn = cb0 + j*16;
    float bv = 0.f;
    if constexpr (EPI==EPI_BIAS || EPI==EPI_VT) bv = bz[cn];
    #pragma unroll
    for (int i=0;i<4;i++){
      #pragma unroll
      for (int p=0;p<4;p++){
        const int row = rb0 + i*16 + p;
        float v = acc[i][j][p];
        if constexpr (EPI==EPI_SCALE) v *= scale;
        if constexpr (EPI==EPI_BIAS)  v += bv;
        if constexpr (EPI==EPI_VT) {
          v += bv;
          const int bb = row>>8, tt = row&255, hh = cn>>7, dd = cn&127;
          C[((long long)((bb*8+hh)*128+dd)<<8) + tt] = f2b(v);
        } else {
          C[(long long)row*ldc + cn] = f2b(v);
        }
      }
    }
  }
}

// ============================================================================
// Split-bf16 NT GEMM: A ~ Ah+Al, B ~ Bh+Bl; acc += Al*Bh + Ah*Bl + Ah*Bh.
enum { SP_GELU_SPLIT=0, SP_BIAS_SPLIT=1, SP_SCALE_F32=2, SP_QBG_F32=3 };

template<int EPI>
__global__ __launch_bounds__(256,2)
void gemm_nt_split(const u16* __restrict__ Ah_, const u16* __restrict__ Al_, long long lda,
                   const u16* __restrict__ Bh_, const u16* __restrict__ Bl_, long long ldb,
                   void* __restrict__ C0, void* __restrict__ C1, long long ldc,
                   const float* __restrict__ bias, float scale, int K)
{
  __shared__ u16 AsH[128*32];
  __shared__ u16 AsL[128*32];
  __shared__ u16 BsH[128*32];
  __shared__ u16 BsL[128*32];
  const int m0 = blockIdx.y*128, n0 = blockIdx.x*128;
  const int t  = threadIdx.x;
  const int lane = t & 63, wv = t >> 6;
  const int wm = (wv>>1)*64, wn = (wv&1)*64;

  const long long arow = (long long)(m0 + (t>>2))*lda + (t&3)*8;
  const long long brow = (long long)(n0 + (t>>2))*ldb + (t&3)*8;
  const u16* gah0 = Ah_ + arow;  const u16* gah1 = gah0 + 64*lda;
  const u16* gal0 = Al_ + arow;  const u16* gal1 = gal0 + 64*lda;
  const u16* gbh0 = Bh_ + brow;  const u16* gbh1 = gbh0 + 64*ldb;
  const u16* gbl0 = Bl_ + brow;  const u16* gbl1 = gbl0 + 64*ldb;
  uint4* sAH = (uint4*)AsH;  uint4* sAL = (uint4*)AsL;
  uint4* sBH = (uint4*)BsH;  uint4* sBL = (uint4*)BsL;

  f32x4 acc[4][4];
  #pragma unroll
  for (int i=0;i<4;i++)
    #pragma unroll
    for (int j=0;j<4;j++) acc[i][j] = (f32x4){0.f,0.f,0.f,0.f};

  const int foff = (lane&15)*32 + ((lane>>4)*8);
  const short8* arh = (const short8*)(AsH + wm*32 + foff);
  const short8* arl = (const short8*)(AsL + wm*32 + foff);
  const short8* brh = (const short8*)(BsH + wn*32 + foff);
  const short8* brl = (const short8*)(BsL + wn*32 + foff);

  for (int kk = 0; kk < K; kk += 32) {
    const uint4 ah0 = *(const uint4*)gah0;  const uint4 ah1 = *(const uint4*)gah1;
    const uint4 al0 = *(const uint4*)gal0;  const uint4 al1 = *(const uint4*)gal1;
    const uint4 bh0 = *(const uint4*)gbh0;  const uint4 bh1 = *(const uint4*)gbh1;
    const uint4 bl0 = *(const uint4*)gbl0;  const uint4 bl1 = *(const uint4*)gbl1;
    gah0 += 32; gah1 += 32; gal0 += 32; gal1 += 32;
    gbh0 += 32; gbh1 += 32; gbl0 += 32; gbl1 += 32;
    __syncthreads();
    sAH[t] = ah0; sAH[256+t] = ah1;
    sAL[t] = al0; sAL[256+t] = al1;
    sBH[t] = bh0; sBH[256+t] = bh1;
    sBL[t] = bl0; sBL[256+t] = bl1;
    __syncthreads();
    short8 fah[4], fal[4], fbh[4], fbl[4];
    #pragma unroll
    for (int i=0;i<4;i++){ fah[i]=arh[i*64]; fal[i]=arl[i*64]; }
    #pragma unroll
    for (int j=0;j<4;j++){ fbh[j]=brh[j*64]; fbl[j]=brl[j*64]; }
    #pragma unroll
    for (int i=0;i<4;i++)
      #pragma unroll
      for (int j=0;j<4;j++){
        acc[i][j] = __builtin_amdgcn_mfma_f32_16x16x32_bf16(fal[i], fbh[j], acc[i][j], 0, 0, 0);
        acc[i][j] = __builtin_amdgcn_mfma_f32_16x16x32_bf16(fah[i], fbl[j], acc[i][j], 0, 0, 0);
        acc[i][j] = __builtin_amdgcn_mfma_f32_16x16x32_bf16(fah[i], fbh[j], acc[i][j], 0, 0, 0);
      }
  }

  const int rb0 = m0 + wm + ((lane>>4)<<2);
  const int cb0 = n0 + wn + (lane&15);
  #pragma unroll
  for (int j=0;j<4;j++){
    const int cn = cb0 + j*16;
    float bv = 0.f;
    if constexpr (EPI==SP_GELU_SPLIT || EPI==SP_BIAS_SPLIT) bv = bias[cn];
    #pragma unroll
    for (int i=0;i<4;i++){
      #pragma unroll
      for (int p=0;p<4;p++){
        const int row = rb0 + i*16 + p;
        float v = acc[i][j][p];
        const long long o = (long long)row*ldc + cn;
        if constexpr (EPI==SP_GELU_SPLIT || EPI==SP_BIAS_SPLIT){
          v += bv;
          if constexpr (EPI==SP_GELU_SPLIT) v = gelu_f(v);
          const u16 h = f2b(v);
          ((u16*)C0)[o] = h;
          ((u16*)C1)[o] = f2b(v - b2f(h));
        }
        if constexpr (EPI==SP_SCALE_F32) ((float*)C0)[o] = v*scale;
        if constexpr (EPI==SP_QBG_F32)   ((float*)C0)[o] = gelu_f(v + bias[(row>>8)*512 + cn]);
      }
    }
  }
}

// ---------------- prep kernels ----------------
__global__ void transpose_w(const float* __restrict__ in, u16* __restrict__ out, int rows, int cols){
  __shared__ float tl[32][33];
  const long long zo = (long long)blockIdx.z*rows*cols;
  const int c0 = blockIdx.x*32, r0 = blockIdx.y*32;
  const int tx = threadIdx.x, ty = threadIdx.y;
  #pragma unroll
  for (int yy=ty; yy<32; yy+=8) tl[yy][tx] = in[zo + (long long)(r0+yy)*cols + (c0+tx)];
  __syncthreads();
  #pragma unroll
  for (int yy=ty; yy<32; yy+=8) out[zo + (long long)(c0+yy)*rows + (r0+tx)] = f2b(tl[tx][yy]);
}

__global__ void split_transpose_w(const float* __restrict__ in, u16* __restrict__ outH,
                                  u16* __restrict__ outL, int rows, int cols){
  __shared__ float tl[32][33];
  const long long zo = (long long)blockIdx.z*rows*cols;
  const int c0 = blockIdx.x*32, r0 = blockIdx.y*32;
  const int tx = threadIdx.x, ty = threadIdx.y;
  #pragma unroll
  for (int yy=ty; yy<32; yy+=8) tl[yy][tx] = in[zo + (long long)(r0+yy)*cols + (c0+tx)];
  __syncthreads();
  #pragma unroll
  for (int yy=ty; yy<32; yy+=8){
    const float v = tl[tx][yy];
    const u16 h = f2b(v);
    const long long o = zo + (long long)(c0+yy)*rows + (r0+tx);
    outH[o] = h;
    outL[o] = f2b(v - b2f(h));
  }
}

__global__ void split_f32_k(const float* __restrict__ in, u16* __restrict__ oh,
                            u16* __restrict__ ol, int n4){
  const int i = blockIdx.x*256 + threadIdx.x;
  if (i < n4){
    const float4 v = ((const float4*)in)[i];
    u16x4 hh, ll;
    hh.x=f2b(v.x); ll.x=f2b(v.x-b2f(hh.x));
    hh.y=f2b(v.y); ll.y=f2b(v.y-b2f(hh.y));
    hh.z=f2b(v.z); ll.z=f2b(v.z-b2f(hh.z));
    hh.w=f2b(v.w); ll.w=f2b(v.w-b2f(hh.w));
    ((u16x4*)oh)[i] = hh;
    ((u16x4*)ol)[i] = ll;
  }
}

__global__ void zero_f32(float* __restrict__ p, int n){
  const int i = blockIdx.x*256 + threadIdx.x;
  if (i < n) p[i] = 0.f;
}

__global__ void ws_report(float* __restrict__ out, int n4, float val){
  const int i = blockIdx.x*256 + threadIdx.x;
  if (i < n4){
    float4 z; z.x = (i==0)? val : 0.f; z.y=0.f; z.z=0.f; z.w=0.f;
    ((float4*)out)[i] = z;
  }
}

// ---------------- pooling (fp32 scores) ----------------
__global__ void row_stats_f32(const float* __restrict__ S, float* __restrict__ mOut,
                              float* __restrict__ dOut){
  const int row = blockIdx.x;
  const float4* p = (const float4*)(S + (long long)row*2048);
  const int tid = threadIdx.x;
  const float4 a = p[2*tid], b = p[2*tid+1];
  float v[8] = {a.x,a.y,a.z,a.w,b.x,b.y,b.z,b.w};
  float mx = v[0];
  #pragma unroll
  for (int k=1;k<8;k++) mx = fmaxf(mx, v[k]);
  mx = blockRedMax(mx);
  float s = 0.f;
  #pragma unroll
  for (int k=0;k<8;k++) s += expf(v[k]-mx);
  s = blockRedSum(s);
  if (tid==0){ mOut[row]=mx; dOut[row]=s; }
}

__global__ void col_mean_f32(const float* __restrict__ S, const float* __restrict__ m,
                             const float* __restrict__ den, float* __restrict__ w){
  const int tc = blockIdx.x*256 + threadIdx.x;
  const int s0 = blockIdx.y*256;
  const float* p = S + (long long)s0*2048 + tc;
  float acc = 0.f;
  for (int s=0;s<256;s++)
    acc += expf(p[(long long)s<<11] - m[s0+s]) * (1.0f/den[s0+s]);
  atomicAdd(&w[tc], acc * (1.f/2048.f));
}

// pooled[b][d] += sum over 128-row t-tile of w[t]*(qfh+qfl)[b][t][d]
// grid (b=4, ttile=16), block 256; coalesced d-major reads, 4 d per thread.
__global__ __launch_bounds__(256)
void pooled_par(const u16* __restrict__ qfh, const u16* __restrict__ qfl,
                const float* __restrict__ w, float* __restrict__ pooled){
  const int b = blockIdx.x, tt0 = blockIdx.y*128;
  const int t = threadIdx.x;
  __shared__ float wsh[128];
  if (t < 128) wsh[t] = w[b*2048 + tt0 + t];
  __syncthreads();
  const long long base = (long long)b*2097152 + (long long)tt0*1024;
  const u16* ph = qfh + base;
  const u16* pl = qfl + base;
  float acc[4] = {0.f,0.f,0.f,0.f};
  for (int s=0; s<128; s++){
    const float wt = wsh[s];
    const long long o = (long long)s*1024;
    #pragma unroll
    for (int k=0;k<4;k++){
      const int dd = t + k*256;
      acc[k] += wt*(b2f(ph[o+dd]) + b2f(pl[o+dd]));
    }
  }
  #pragma unroll
  for (int k=0;k<4;k++) atomicAdd(&pooled[b*1024 + t + k*256], acc[k]);
}

// LayerNorm of pooled -> plbuf (grid 12, block 1024)
__global__ __launch_bounds__(1024)
void pool_ln(const float* __restrict__ pooled, const float* __restrict__ pg,
             const float* __restrict__ pb, float* __restrict__ plbuf){
  const int z = blockIdx.x, r = z>>2, d = threadIdx.x;
  const float v = pooled[z*1024+d];
  const float mean = blockRedSum(v) * (1.f/1024.f);
  const float df = v - mean;
  const float var = blockRedSum(df*df) * (1.f/1024.f);
  plbuf[z*1024+d] = df*rsqrtf(var+1e-5f)*pg[r*1024+d] + pb[r*1024+d];
}

// queries[z][d] = plbuf[z] @ pool_w[r] + pool_b[r]
// grid (z=12, db=8), block 256: 128 d per block, 2 k-slices of 512.
__global__ __launch_bounds__(256)
void query_gemv(const float* __restrict__ plbuf, const float* __restrict__ pw,
                const float* __restrict__ pbias, float* __restrict__ queries){
  const int z = blockIdx.x, r = z>>2, d0 = blockIdx.y*128;
  const int t = threadIdx.x;
  const int d = d0 + (t & 127), ks = t>>7;
  __shared__ float pls[1024];
  __shared__ float red[256];
  for (int i=t; i<1024; i+=256) pls[i] = plbuf[z*1024+i];
  __syncthreads();
  float a = 0.f;
  const float* wp = pw + (long long)r*1048576;
  for (int k=ks*512; k<ks*512+512; k++) a += pls[k]*wp[(long long)k*1024 + d];
  red[t] = a;
  __syncthreads();
  if (t < 128) queries[z*1024+d] = red[t] + red[t+128] + pbias[r*1024+d];
}

// qpart[z][n] = queries[z] @ rel_w1[1024:,:] + rel_b1
// grid (z=12, nb=4), block 256: 128 n per block, 2 k-slices of 512.
__global__ __launch_bounds__(256)
void qpart_par(const float* __restrict__ queries, const float* __restrict__ rw1,
               const float* __restrict__ rb1, float* __restrict__ qpart){
  const int z = blockIdx.x, n0 = blockIdx.y*128;
  const int t = threadIdx.x;
  const int n = n0 + (t & 127), ks = t>>7;
  __shared__ float qs[1024];
  __shared__ float red[256];
  for (int i=t; i<1024; i+=256) qs[i] = queries[z*1024+i];
  __syncthreads();
  float a = 0.f;
  const float* wp = rw1 + 1024*512;
  for (int k=ks*512; k<ks*512+512; k++) a += qs[k]*wp[(long long)k*512 + n];
  red[t] = a;
  __syncthreads();
  if (t < 128) qpart[z*512+n] = red[t] + red[t+128] + rb1[n];
}

// rel = sigmoid(h @ rel_w2 + rel_b2), h fp32; one wave per row
__global__ void rel_score_f32(const float* __restrict__ h, const float* __restrict__ w2,
                              const float* __restrict__ b2p, float* __restrict__ relv){
  const int row = blockIdx.x*4 + (threadIdx.x>>6);
  const int lane = threadIdx.x & 63;
  const float* p = h + (long long)row*512;
  float a = 0.f;
  #pragma unroll
  for (int k=0;k<8;k++){ const int idx = lane + k*64; a += p[idx]*w2[idx]; }
  a = waveRedSum(a);
  if (lane==0){
    const float lg = a + b2p[0];
    relv[row] = 1.f/(1.f+expf(-lg));
  }
}

// ---------------- selection ----------------
__global__ __launch_bounds__(768)
void select_topk(const float* __restrict__ relv, int* __restrict__ selidx,
                 int* __restrict__ neff, int* __restrict__ anyv){
  const int b = blockIdx.x, c = threadIdx.x;
  __shared__ float rv[768];
  __shared__ int cnt;
  rv[c] = relv[(((c>>8)*4)+b)*256 + (c&255)];
  if (c==0) cnt = 0;
  __syncthreads();
  const float mine = rv[c];
  const bool valid = (mine >= 0.5f);
  int rank = 0;
  for (int j=0;j<768;j++){
    const float vj = rv[j];
    if (vj >= 0.5f && (vj > mine || (vj == mine && j < c))) rank++;
  }
  if (valid && rank < 256){
    const int s = atomicAdd(&cnt, 1);
    selidx[b*256 + s] = c;
  }
  __syncthreads();
  if (c==0){ neff[b] = cnt; anyv[b] = (cnt>0) ? 1 : 0; }
}

__global__ void gather_sel(const u16* __restrict__ rb16, const int* __restrict__ selidx,
                           const int* __restrict__ neff, u16* __restrict__ seltok){
  const int slot = blockIdx.x, b = blockIdx.y, tid = threadIdx.x;
  uint2 val; val.x=0u; val.y=0u;
  if (slot < neff[b]){
    const int c = selidx[b*256+slot];
    const uint2* src = (const uint2*)(rb16 + (long long)(((c>>8)*4+b)*256 + (c&255))*1024);
    val = src[tid];
  }
  ((uint2*)(seltok + (long long)(b*256+slot)*1024))[tid] = val;
}

// masked softmax over key slots (one wave per row of 256)
__global__ void attn_softmax(u16* __restrict__ S, const int* __restrict__ neff){
  const int ri = blockIdx.x*4 + (threadIdx.x>>6);
  const int lane = threadIdx.x & 63;
  const int b = ri >> 14;
  const int ne = neff[b];
  u16* p = S + (long long)ri*256 + lane*4;
  if (ne == 0){ uint2 zz; zz.x=0u; zz.y=0u; *(uint2*)p = zz; return; }
  uint2 raw = *(const uint2*)p;
  u16 uu[4] = {(u16)(raw.x&0xffffu),(u16)(raw.x>>16),(u16)(raw.y&0xffffu),(u16)(raw.y>>16)};
  float xs[4];
  #pragma unroll
  for (int q2=0;q2<4;q2++){ const int tt = lane*4+q2; xs[q2] = (tt<ne)? b2f(uu[q2]) : -1e30f; }
  float mx = fmaxf(fmaxf(xs[0],xs[1]),fmaxf(xs[2],xs[3]));
  mx = waveRedMax(mx);
  float e[4]; float sm=0.f;
  #pragma unroll
  for (int q2=0;q2<4;q2++){ e[q2] = (lane*4+q2<ne)? expf(xs[q2]-mx) : 0.f; sm += e[q2]; }
  sm = waveRedSum(sm);
  const float inv = 1.f/sm;
  #pragma unroll
  for (int q2=0;q2<4;q2++) uu[q2] = f2b(e[q2]*inv);
  raw.x = (u32)uu[0] | ((u32)uu[1]<<16);
  raw.y = (u32)uu[2] | ((u32)uu[3]<<16);
  *(uint2*)p = raw;
}

// residual + LayerNorm + any_valid select
__global__ void final_ln(const float* __restrict__ x, const u16* __restrict__ fused,
                         const float* __restrict__ g, const float* __restrict__ bb,
                         const int* __restrict__ anyv, float* __restrict__ out){
  const int row = blockIdx.x; const int b = row>>11; const int tid = threadIdx.x;
  const float4 xv = ((const float4*)(x + (long long)row*1024))[tid];
  const uint2 fv = ((const uint2*)(fused + (long long)row*1024))[tid];
  const float e0 = xv.x + b2f((u16)(fv.x&0xffffu));
  const float e1 = xv.y + b2f((u16)(fv.x>>16));
  const float e2 = xv.z + b2f((u16)(fv.y&0xffffu));
  const float e3 = xv.w + b2f((u16)(fv.y>>16));
  const float mean = blockRedSum(e0+e1+e2+e3) * (1.f/1024.f);
  const float d0=e0-mean, d1=e1-mean, d2=e2-mean, d3=e3-mean;
  const float var = blockRedSum(d0*d0+d1*d1+d2*d2+d3*d3) * (1.f/1024.f);
  const float inv = rsqrtf(var + 1e-5f);
  const float4 gv = ((const float4*)g)[tid];
  const float4 bv = ((const float4*)bb)[tid];
  float4 o;
  if (anyv[b]){
    o.x = d0*inv*gv.x + bv.x; o.y = d1*inv*gv.y + bv.y;
    o.z = d2*inv*gv.z + bv.z; o.w = d3*inv*gv.w + bv.w;
  } else o = xv;
  ((float4*)(out + (long long)row*1024))[tid] = o;
}

// ============================================================================
extern "C" void kernel_launch(void* const* d_in, const int* in_sizes, int n_in,
                              void* d_out, int out_size, void* d_ws, size_t ws_size,
                              hipStream_t stream) {
  (void)in_sizes; (void)n_in;
  const float* x      = (const float*)d_in[0];
  const float* retr   = (const float*)d_in[1];
  const float* qg_w1  = (const float*)d_in[2];
  const float* qg_b1  = (const float*)d_in[3];
  const float* qg_w2  = (const float*)d_in[4];
  const float* qg_b2  = (const float*)d_in[5];
  const float* pln_g  = (const float*)d_in[6];
  const float* pln_b  = (const float*)d_in[7];
  const float* pool_w = (const float*)d_in[8];
  const float* pool_b = (const float*)d_in[9];
  const float* rel_w1 = (const float*)d_in[10];
  const float* rel_b1 = (const float*)d_in[11];
  const float* rel_w2 = (const float*)d_in[12];
  const float* rel_b2 = (const float*)d_in[13];
  const float* in_w   = (const float*)d_in[14];
  const float* in_b   = (const float*)d_in[15];
  const float* out_w  = (const float*)d_in[16];
  const float* out_b  = (const float*)d_in[17];
  const float* fln_g  = (const float*)d_in[18];
  const float* fln_b  = (const float*)d_in[19];
  float* out = (float*)d_out;
  char* ws = (char*)d_ws;

  const size_t MB = 1u<<20;
  const size_t REQUIRED = 131*MB;
  if (ws_size < REQUIRED){
    ws_report<<<(out_size/4 + 255)/256, 256, 0, stream>>>(out, out_size/4, (float)(ws_size>>20));
    return;
  }

  // ---- layout (MB offsets; lifetimes commented) ----
  u16* qg1Th = (u16*)(ws + 0*MB);    // 6   [A]
  u16* qg1Tl = (u16*)(ws + 6*MB);    // 6   [A]
  u16* qg2Th = (u16*)(ws + 12*MB);   // 6   [A]
  u16* qg2Tl = (u16*)(ws + 18*MB);   // 6   [A]
  u16* xh    = (u16*)(ws + 24*MB);   // 16  [A, F]  (= bf16(x))
  u16* xl    = (u16*)(ws + 40*MB);   // 16  [A]
  u16* rh    = (u16*)(ws + 56*MB);   // 6   [D, E]  (= bf16(retr))
  u16* rl    = (u16*)(ws + 62*MB);   // 6   [D]
  u16* relTh = (u16*)(ws + 68*MB);   // 1   [D]
  u16* relTl = (u16*)(ws + 69*MB);   // 1   [D]
  u16* qfh   = (u16*)(ws + 70*MB);   // 16  [A->B] per retriever
  u16* qfl   = (u16*)(ws + 86*MB);   // 16  [A->B]
  // region 102..118: t1h/t1l (A) | scores fp32 (B) | hbuf (D) | attnout (F)
  u16*   t1h    = (u16*)(ws + 102*MB);  // 8
  u16*   t1l    = (u16*)(ws + 110*MB);  // 8
  float* scores = (float*)(ws + 102*MB);// 16
  float* hbuf   = (float*)(ws + 102*MB);// 6
  u16*   attnout= (u16*)(ws + 102*MB);  // 16
  // stage F reuse of dead zones (each 2 MB):
  u16* qbuf   = (u16*)(ws + 0*MB);    // 16 (over qg1T/qg2T, dead after A)
  u16* fused  = (u16*)(ws + 0*MB);    // 16 (over qbuf, dead after QK^T)
  u16* inT    = (u16*)(ws + 40*MB);   // 6  (over xl, dead after A)
  u16* outT   = (u16*)(ws + 46*MB);   // 2
  u16* seltok = (u16*)(ws + 48*MB);   // 2  [4][256][1024] bf16
  u16* kbuf   = (u16*)(ws + 50*MB);   // 2
  u16* VT     = (u16*)(ws + 52*MB);   // 2  (54..56 spare)
  u16* Sattn  = (u16*)(ws + 70*MB);   // 32 (over qfh/qfl, dead after pooling)
  // smalls at 118..
  char* SM = ws + 118*MB;
  float* wbuf    = (float*)(SM);            // 96 KB [12][2048]
  float* pooledB = (float*)(SM + 98304);    // 48 KB [12][1024] (contiguous after wbuf)
  float* plbuf   = (float*)(SM + 147456);   // 48 KB [12][1024]
  float* queries = (float*)(SM + 196608);   // 48 KB
  float* qpart   = (float*)(SM + 245760);   // 24 KB
  float* relv    = (float*)(SM + 270336);   // 12 KB
  int*   selidx  = (int*)(SM + 282624);     //  4 KB
  int*   neff    = (int*)(SM + 286720);
  int*   anyv    = (int*)(SM + 286784);
  float* mrow    = (float*)(SM + 286848);   //  8 KB [2048]
  float* drow    = (float*)(SM + 295040);   //  8 KB

  dim3 b256(256);
  dim3 tb(32,8);

  // --- prep: split weights/activations ---
  split_transpose_w<<<dim3(32,32,3), tb, 0, stream>>>(qg_w1, qg1Th, qg1Tl, 1024, 1024);
  split_transpose_w<<<dim3(32,32,3), tb, 0, stream>>>(qg_w2, qg2Th, qg2Tl, 1024, 1024);
  split_transpose_w<<<dim3(16,32,1), tb, 0, stream>>>(rel_w1, relTh, relTl, 1024, 512);
  split_f32_k<<<8192, b256, 0, stream>>>(x,    xh, xl, 2097152);
  split_f32_k<<<3072, b256, 0, stream>>>(retr, rh, rl,  786432);
  zero_f32<<<144, b256, 0, stream>>>(wbuf, 36864);   // wbuf[24576] + pooledB[12288]

  // --- stages A+B per retriever (split precision) ---
  for (int r = 0; r < 3; r++){
    const long long wo = (long long)r*1048576;
    for (int hf = 0; hf < 2; hf++){
      const long long xo = (long long)hf*4194304;   // 4096 rows * 1024
      gemm_nt_split<SP_GELU_SPLIT><<<dim3(8,32), b256, 0, stream>>>(
          xh+xo, xl+xo, 1024,  qg1Th+wo, qg1Tl+wo, 1024,
          t1h, t1l, 1024,  qg_b1+r*1024, 1.f, 1024);
      gemm_nt_split<SP_BIAS_SPLIT><<<dim3(8,32), b256, 0, stream>>>(
          t1h, t1l, 1024,  qg2Th+wo, qg2Tl+wo, 1024,
          qfh+xo, qfl+xo, 1024,  qg_b2+r*1024, 1.f, 1024);
    }
    for (int b = 0; b < 4; b++){
      const long long qo = (long long)b*2097152;
      gemm_nt_split<SP_SCALE_F32><<<dim3(16,16), b256, 0, stream>>>(
          qfh+qo, qfl+qo, 1024,  qfh+qo, qfl+qo, 1024,
          scores, nullptr, 2048,  nullptr, 0.03125f, 1024);
      row_stats_f32<<<2048, b256, 0, stream>>>(scores, mrow, drow);
      col_mean_f32<<<dim3(8,8), b256, 0, stream>>>(scores, mrow, drow, wbuf + (r*4+b)*2048);
    }
    pooled_par<<<dim3(4,16), b256, 0, stream>>>(qfh, qfl, wbuf + r*8192, pooledB + r*4096);
  }
  pool_ln<<<12, 1024, 0, stream>>>(pooledB, pln_g, pln_b, plbuf);
  query_gemv<<<dim3(12,8), b256, 0, stream>>>(plbuf, pool_w, pool_b, queries);

  // --- stage D: relevance scorer (split GEMM, fp32 h) ---
  qpart_par<<<dim3(12,4), b256, 0, stream>>>(queries, rel_w1, rel_b1, qpart);
  gemm_nt_split<SP_QBG_F32><<<dim3(4,24), b256, 0, stream>>>(
      rh, rl, 1024,  relTh, relTl, 1024,  hbuf, nullptr, 512,  qpart, 1.f, 1024);
  rel_score_f32<<<768, b256, 0, stream>>>(hbuf, rel_w2, rel_b2, relv);

  // --- stage E: selection ---
  select_topk<<<4, 768, 0, stream>>>(relv, selidx, neff, anyv);
  gather_sel<<<dim3(256,4), b256, 0, stream>>>(rh, selidx, neff, seltok);

  // --- stage F: fusion cross-attention (plain bf16) ---
  transpose_w<<<dim3(32,32,3), tb, 0, stream>>>(in_w,  inT,  1024, 1024);
  transpose_w<<<dim3(32,32,1), tb, 0, stream>>>(out_w, outT, 1024, 1024);
  gemm_nt<EPI_BIAS><<<dim3(8,64,1), b256, 0, stream>>>(
      xh,1024,0,0,  inT,1024,0,0,  qbuf,1024,0,0,  in_b,0, 1.f, 1024, 1);
  gemm_nt<EPI_BIAS><<<dim3(8,8,1), b256, 0, stream>>>(
      seltok,1024,0,0,  inT+1048576,1024,0,0,  kbuf,1024,0,0,  in_b+1024,0, 1.f, 1024, 1);
  gemm_nt<EPI_VT><<<dim3(8,8,1), b256, 0, stream>>>(
      seltok,1024,0,0,  inT+2097152,1024,0,0,  VT,0,0,0,  in_b+2048,0, 1.f, 1024, 1);
  gemm_nt<EPI_SCALE><<<dim3(2,16,32), b256, 0, stream>>>(
      qbuf,1024,2097152,128,  kbuf,1024,262144,128,  Sattn,256,4194304,524288,
      (const float*)nullptr,0, 0.08838834764831845f, 128, 8);
  attn_softmax<<<16384, b256, 0, stream>>>(Sattn, neff);
  gemm_nt<EPI_NONE><<<dim3(1,16,32), b256, 0, stream>>>(
      Sattn,256,4194304,524288,  VT,256,262144,32768,  attnout,1024,2097152,128,
      (const float*)nullptr,0, 1.f, 256, 8);
  gemm_nt<EPI_BIAS><<<dim3(8,64,1), b256, 0, stream>>>(
      attnout,1024,0,0,  outT,1024,0,0,  fused,1024,0,0,  out_b,0, 1.f, 1024, 1);
  final_ln<<<8192, b256, 0, stream>>>(x, fused, fln_g, fln_b, anyv, out);
}

// Round 6
// 1828.879 us; speedup vs baseline: 1.4515x; 1.4105x over previous
//
#include <hip/hip_runtime.h>
#include <math.h>

// ============================================================================
// RetrievalAugmentedProcessor — MI355X (gfx950)
// B=4 S=2048 D=1024 R=3 K=256 MAXR=256 H=8 HD=128
// R6: kill the remaining latency-bound GEMV tail (rocprof: query_gemv 201us,
//     VGPR=8, 125 GB/s, 0.77% VALU -> stride-4KB k-loop serialization).
//     query_gemv/qpart_par -> k-outer accum kernels (coalesced row reads +
//     atomicAdd into bias-initialized outputs); col_mean s-parallelism x4.
//     GEMM cores unchanged (green, absmax 0.031).
// ============================================================================

typedef unsigned short u16;
typedef unsigned int   u32;
typedef __attribute__((ext_vector_type(8))) short short8;   // 8 bf16
typedef __attribute__((ext_vector_type(4))) float f32x4;    // MFMA acc
typedef __attribute__((ext_vector_type(4))) u16  u16x4;

__device__ __forceinline__ float b2f(u16 u){ union{float f;u32 i;} x; x.i=((u32)u)<<16; return x.f; }
__device__ __forceinline__ u16 f2b(float f){ union{float f;u32 i;} x; x.f=f; u32 r=x.i+0x7fffu+((x.i>>16)&1u); return (u16)(r>>16); }
__device__ __forceinline__ float gelu_f(float v){ return 0.5f*v*(1.f+erff(v*0.70710678118654752f)); }

// ---------------- reductions ----------------
__device__ __forceinline__ float waveRedSum(float v){
  #pragma unroll
  for (int o=32;o>0;o>>=1) v += __shfl_xor(v,o);
  return v;
}
__device__ __forceinline__ float waveRedMax(float v){
  #pragma unroll
  for (int o=32;o>0;o>>=1) v = fmaxf(v, __shfl_xor(v,o));
  return v;
}
__device__ float blockRedSum(float v){
  __shared__ float tmp[17];
  const int lane = threadIdx.x&63, wv = threadIdx.x>>6, nw = blockDim.x>>6;
  v = waveRedSum(v);
  __syncthreads();
  if (lane==0) tmp[wv]=v;
  __syncthreads();
  if (threadIdx.x==0){ float s=tmp[0]; for(int i=1;i<nw;i++) s+=tmp[i]; tmp[16]=s; }
  __syncthreads();
  return tmp[16];
}
__device__ float blockRedMax(float v){
  __shared__ float tmp[17];
  const int lane = threadIdx.x&63, wv = threadIdx.x>>6, nw = blockDim.x>>6;
  v = waveRedMax(v);
  __syncthreads();
  if (lane==0) tmp[wv]=v;
  __syncthreads();
  if (threadIdx.x==0){ float s=tmp[0]; for(int i=1;i<nw;i++) s=fmaxf(s,tmp[i]); tmp[16]=s; }
  __syncthreads();
  return tmp[16];
}

// ============================================================================
// Plain bf16 NT GEMM (stage F).
enum { EPI_NONE=0, EPI_BIAS=1, EPI_SCALE=3, EPI_VT=5 };

template<int EPI>
__global__ __launch_bounds__(256,2)
void gemm_nt(const u16* __restrict__ Ag, long long lda, long long sA1, long long sA2,
             const u16* __restrict__ Bg, long long ldb, long long sB1, long long sB2,
             u16* __restrict__ Cg, long long ldc, long long sC1, long long sC2,
             const float* __restrict__ bias, long long sBias,
             float scale, int K, int H)
{
  __shared__ u16 As[128*32];
  __shared__ u16 Bs[128*32];
  const int z  = blockIdx.z;
  const int zb = z / H, zh = z - zb*H;
  const u16* A = Ag + zb*sA1 + zh*sA2;
  const u16* B = Bg + zb*sB1 + zh*sB2;
  const int m0 = blockIdx.y*128, n0 = blockIdx.x*128;
  const int t  = threadIdx.x;
  const int lane = t & 63, wv = t >> 6;
  const int wm = (wv>>1)*64, wn = (wv&1)*64;

  const u16* ga0 = A + (long long)(m0 + (t>>2))*lda + (t&3)*8;
  const u16* ga1 = ga0 + 64*lda;
  const u16* gb0 = B + (long long)(n0 + (t>>2))*ldb + (t&3)*8;
  const u16* gb1 = gb0 + 64*ldb;
  uint4* sA = (uint4*)As;
  uint4* sB = (uint4*)Bs;

  f32x4 acc[4][4];
  #pragma unroll
  for (int i=0;i<4;i++)
    #pragma unroll
    for (int j=0;j<4;j++) acc[i][j] = (f32x4){0.f,0.f,0.f,0.f};

  const short8* arp = (const short8*)(As + (wm + (lane&15))*32 + ((lane>>4)*8));
  const short8* brp = (const short8*)(Bs + (wn + (lane&15))*32 + ((lane>>4)*8));

  for (int kk = 0; kk < K; kk += 32) {
    const uint4 a0 = *(const uint4*)ga0;
    const uint4 a1 = *(const uint4*)ga1;
    const uint4 b0 = *(const uint4*)gb0;
    const uint4 b1 = *(const uint4*)gb1;
    ga0 += 32; ga1 += 32; gb0 += 32; gb1 += 32;
    __syncthreads();
    sA[t] = a0; sA[256+t] = a1;
    sB[t] = b0; sB[256+t] = b1;
    __syncthreads();
    short8 af[4], bfr[4];
    #pragma unroll
    for (int i=0;i<4;i++) af[i]  = arp[i*64];
    #pragma unroll
    for (int j=0;j<4;j++) bfr[j] = brp[j*64];
    #pragma unroll
    for (int i=0;i<4;i++)
      #pragma unroll
      for (int j=0;j<4;j++)
        acc[i][j] = __builtin_amdgcn_mfma_f32_16x16x32_bf16(af[i], bfr[j], acc[i][j], 0, 0, 0);
  }

  u16* C = Cg + zb*sC1 + zh*sC2;
  const float* bz = bias + zb*sBias;
  const int rb0 = m0 + wm + ((lane>>4)<<2);
  const int cb0 = n0 + wn + (lane&15);
  #pragma unroll
  for (int j=0;j<4;j++){
    const int cn = cb0 + j*16;
    float bv = 0.f;
    if constexpr (EPI==EPI_BIAS || EPI==EPI_VT) bv = bz[cn];
    #pragma unroll
    for (int i=0;i<4;i++){
      #pragma unroll
      for (int p=0;p<4;p++){
        const int row = rb0 + i*16 + p;
        float v = acc[i][j][p];
        if constexpr (EPI==EPI_SCALE) v *= scale;
        if constexpr (EPI==EPI_BIAS)  v += bv;
        if constexpr (EPI==EPI_VT) {
          v += bv;
          const int bb = row>>8, tt = row&255, hh = cn>>7, dd = cn&127;
          C[((long long)((bb*8+hh)*128+dd)<<8) + tt] = f2b(v);
        } else {
          C[(long long)row*ldc + cn] = f2b(v);
        }
      }
    }
  }
}

// ============================================================================
// Split-bf16 NT GEMM: A ~ Ah+Al, B ~ Bh+Bl; acc += Al*Bh + Ah*Bl + Ah*Bh.
enum { SP_GELU_SPLIT=0, SP_BIAS_SPLIT=1, SP_SCALE_F32=2, SP_QBG_F32=3 };

template<int EPI>
__global__ __launch_bounds__(256,2)
void gemm_nt_split(const u16* __restrict__ Ah_, const u16* __restrict__ Al_, long long lda,
                   const u16* __restrict__ Bh_, const u16* __restrict__ Bl_, long long ldb,
                   void* __restrict__ C0, void* __restrict__ C1, long long ldc,
                   const float* __restrict__ bias, float scale, int K)
{
  __shared__ u16 AsH[128*32];
  __shared__ u16 AsL[128*32];
  __shared__ u16 BsH[128*32];
  __shared__ u16 BsL[128*32];
  const int m0 = blockIdx.y*128, n0 = blockIdx.x*128;
  const int t  = threadIdx.x;
  const int lane = t & 63, wv = t >> 6;
  const int wm = (wv>>1)*64, wn = (wv&1)*64;

  const long long arow = (long long)(m0 + (t>>2))*lda + (t&3)*8;
  const long long brow = (long long)(n0 + (t>>2))*ldb + (t&3)*8;
  const u16* gah0 = Ah_ + arow;  const u16* gah1 = gah0 + 64*lda;
  const u16* gal0 = Al_ + arow;  const u16* gal1 = gal0 + 64*lda;
  const u16* gbh0 = Bh_ + brow;  const u16* gbh1 = gbh0 + 64*ldb;
  const u16* gbl0 = Bl_ + brow;  const u16* gbl1 = gbl0 + 64*ldb;
  uint4* sAH = (uint4*)AsH;  uint4* sAL = (uint4*)AsL;
  uint4* sBH = (uint4*)BsH;  uint4* sBL = (uint4*)BsL;

  f32x4 acc[4][4];
  #pragma unroll
  for (int i=0;i<4;i++)
    #pragma unroll
    for (int j=0;j<4;j++) acc[i][j] = (f32x4){0.f,0.f,0.f,0.f};

  const int foff = (lane&15)*32 + ((lane>>4)*8);
  const short8* arh = (const short8*)(AsH + wm*32 + foff);
  const short8* arl = (const short8*)(AsL + wm*32 + foff);
  const short8* brh = (const short8*)(BsH + wn*32 + foff);
  const short8* brl = (const short8*)(BsL + wn*32 + foff);

  for (int kk = 0; kk < K; kk += 32) {
    const uint4 ah0 = *(const uint4*)gah0;  const uint4 ah1 = *(const uint4*)gah1;
    const uint4 al0 = *(const uint4*)gal0;  const uint4 al1 = *(const uint4*)gal1;
    const uint4 bh0 = *(const uint4*)gbh0;  const uint4 bh1 = *(const uint4*)gbh1;
    const uint4 bl0 = *(const uint4*)gbl0;  const uint4 bl1 = *(const uint4*)gbl1;
    gah0 += 32; gah1 += 32; gal0 += 32; gal1 += 32;
    gbh0 += 32; gbh1 += 32; gbl0 += 32; gbl1 += 32;
    __syncthreads();
    sAH[t] = ah0; sAH[256+t] = ah1;
    sAL[t] = al0; sAL[256+t] = al1;
    sBH[t] = bh0; sBH[256+t] = bh1;
    sBL[t] = bl0; sBL[256+t] = bl1;
    __syncthreads();
    short8 fah[4], fal[4], fbh[4], fbl[4];
    #pragma unroll
    for (int i=0;i<4;i++){ fah[i]=arh[i*64]; fal[i]=arl[i*64]; }
    #pragma unroll
    for (int j=0;j<4;j++){ fbh[j]=brh[j*64]; fbl[j]=brl[j*64]; }
    #pragma unroll
    for (int i=0;i<4;i++)
      #pragma unroll
      for (int j=0;j<4;j++){
        acc[i][j] = __builtin_amdgcn_mfma_f32_16x16x32_bf16(fal[i], fbh[j], acc[i][j], 0, 0, 0);
        acc[i][j] = __builtin_amdgcn_mfma_f32_16x16x32_bf16(fah[i], fbl[j], acc[i][j], 0, 0, 0);
        acc[i][j] = __builtin_amdgcn_mfma_f32_16x16x32_bf16(fah[i], fbh[j], acc[i][j], 0, 0, 0);
      }
  }

  const int rb0 = m0 + wm + ((lane>>4)<<2);
  const int cb0 = n0 + wn + (lane&15);
  #pragma unroll
  for (int j=0;j<4;j++){
    const int cn = cb0 + j*16;
    float bv = 0.f;
    if constexpr (EPI==SP_GELU_SPLIT || EPI==SP_BIAS_SPLIT) bv = bias[cn];
    #pragma unroll
    for (int i=0;i<4;i++){
      #pragma unroll
      for (int p=0;p<4;p++){
        const int row = rb0 + i*16 + p;
        float v = acc[i][j][p];
        const long long o = (long long)row*ldc + cn;
        if constexpr (EPI==SP_GELU_SPLIT || EPI==SP_BIAS_SPLIT){
          v += bv;
          if constexpr (EPI==SP_GELU_SPLIT) v = gelu_f(v);
          const u16 h = f2b(v);
          ((u16*)C0)[o] = h;
          ((u16*)C1)[o] = f2b(v - b2f(h));
        }
        if constexpr (EPI==SP_SCALE_F32) ((float*)C0)[o] = v*scale;
        if constexpr (EPI==SP_QBG_F32)   ((float*)C0)[o] = gelu_f(v + bias[(row>>8)*512 + cn]);
      }
    }
  }
}

// ---------------- prep kernels ----------------
__global__ void transpose_w(const float* __restrict__ in, u16* __restrict__ out, int rows, int cols){
  __shared__ float tl[32][33];
  const long long zo = (long long)blockIdx.z*rows*cols;
  const int c0 = blockIdx.x*32, r0 = blockIdx.y*32;
  const int tx = threadIdx.x, ty = threadIdx.y;
  #pragma unroll
  for (int yy=ty; yy<32; yy+=8) tl[yy][tx] = in[zo + (long long)(r0+yy)*cols + (c0+tx)];
  __syncthreads();
  #pragma unroll
  for (int yy=ty; yy<32; yy+=8) out[zo + (long long)(c0+yy)*rows + (r0+tx)] = f2b(tl[tx][yy]);
}

__global__ void split_transpose_w(const float* __restrict__ in, u16* __restrict__ outH,
                                  u16* __restrict__ outL, int rows, int cols){
  __shared__ float tl[32][33];
  const long long zo = (long long)blockIdx.z*rows*cols;
  const int c0 = blockIdx.x*32, r0 = blockIdx.y*32;
  const int tx = threadIdx.x, ty = threadIdx.y;
  #pragma unroll
  for (int yy=ty; yy<32; yy+=8) tl[yy][tx] = in[zo + (long long)(r0+yy)*cols + (c0+tx)];
  __syncthreads();
  #pragma unroll
  for (int yy=ty; yy<32; yy+=8){
    const float v = tl[tx][yy];
    const u16 h = f2b(v);
    const long long o = zo + (long long)(c0+yy)*rows + (r0+tx);
    outH[o] = h;
    outL[o] = f2b(v - b2f(h));
  }
}

__global__ void split_f32_k(const float* __restrict__ in, u16* __restrict__ oh,
                            u16* __restrict__ ol, int n4){
  const int i = blockIdx.x*256 + threadIdx.x;
  if (i < n4){
    const float4 v = ((const float4*)in)[i];
    u16x4 hh, ll;
    hh.x=f2b(v.x); ll.x=f2b(v.x-b2f(hh.x));
    hh.y=f2b(v.y); ll.y=f2b(v.y-b2f(hh.y));
    hh.z=f2b(v.z); ll.z=f2b(v.z-b2f(hh.z));
    hh.w=f2b(v.w); ll.w=f2b(v.w-b2f(hh.w));
    ((u16x4*)oh)[i] = hh;
    ((u16x4*)ol)[i] = ll;
  }
}

__global__ void zero_f32(float* __restrict__ p, int n){
  const int i = blockIdx.x*256 + threadIdx.x;
  if (i < n) p[i] = 0.f;
}

__global__ void init_queries(const float* __restrict__ pb, float* __restrict__ q){
  const int i = blockIdx.x*256 + threadIdx.x;   // 12*1024
  if (i < 12288) q[i] = pb[(i>>12)*1024 + (i&1023)];
}
__global__ void init_qpart(const float* __restrict__ rb1, float* __restrict__ qp){
  const int i = blockIdx.x*256 + threadIdx.x;   // 12*512
  if (i < 6144) qp[i] = rb1[i&511];
}

__global__ void ws_report(float* __restrict__ out, int n4, float val){
  const int i = blockIdx.x*256 + threadIdx.x;
  if (i < n4){
    float4 z; z.x = (i==0)? val : 0.f; z.y=0.f; z.z=0.f; z.w=0.f;
    ((float4*)out)[i] = z;
  }
}

// ---------------- pooling (fp32 scores) ----------------
__global__ void row_stats_f32(const float* __restrict__ S, float* __restrict__ mOut,
                              float* __restrict__ dOut){
  const int row = blockIdx.x;
  const float4* p = (const float4*)(S + (long long)row*2048);
  const int tid = threadIdx.x;
  const float4 a = p[2*tid], b = p[2*tid+1];
  float v[8] = {a.x,a.y,a.z,a.w,b.x,b.y,b.z,b.w};
  float mx = v[0];
  #pragma unroll
  for (int k=1;k<8;k++) mx = fmaxf(mx, v[k]);
  mx = blockRedMax(mx);
  float s = 0.f;
  #pragma unroll
  for (int k=0;k<8;k++) s += expf(v[k]-mx);
  s = blockRedSum(s);
  if (tid==0){ mOut[row]=mx; dOut[row]=s; }
}

// grid (8 col-tiles, 32 s-tiles of 64)
__global__ void col_mean_f32(const float* __restrict__ S, const float* __restrict__ m,
                             const float* __restrict__ den, float* __restrict__ w){
  const int tc = blockIdx.x*256 + threadIdx.x;
  const int s0 = blockIdx.y*64;
  const float* p = S + (long long)s0*2048 + tc;
  float acc = 0.f;
  for (int s=0;s<64;s++)
    acc += expf(p[(long long)s<<11] - m[s0+s]) * (1.0f/den[s0+s]);
  atomicAdd(&w[tc], acc * (1.f/2048.f));
}

// pooled[b][d] += sum over 128-row t-tile of w[t]*(qfh+qfl)[b][t][d]
__global__ __launch_bounds__(256)
void pooled_par(const u16* __restrict__ qfh, const u16* __restrict__ qfl,
                const float* __restrict__ w, float* __restrict__ pooled){
  const int b = blockIdx.x, tt0 = blockIdx.y*128;
  const int t = threadIdx.x;
  __shared__ float wsh[128];
  if (t < 128) wsh[t] = w[b*2048 + tt0 + t];
  __syncthreads();
  const long long base = (long long)b*2097152 + (long long)tt0*1024;
  const u16* ph = qfh + base;
  const u16* pl = qfl + base;
  float acc[4] = {0.f,0.f,0.f,0.f};
  for (int s=0; s<128; s++){
    const float wt = wsh[s];
    const long long o = (long long)s*1024;
    #pragma unroll
    for (int k=0;k<4;k++){
      const int dd = t + k*256;
      acc[k] += wt*(b2f(ph[o+dd]) + b2f(pl[o+dd]));
    }
  }
  #pragma unroll
  for (int k=0;k<4;k++) atomicAdd(&pooled[b*1024 + t + k*256], acc[k]);
}

// LayerNorm of pooled -> plbuf (grid 12, block 1024)
__global__ __launch_bounds__(1024)
void pool_ln(const float* __restrict__ pooled, const float* __restrict__ pg,
             const float* __restrict__ pb, float* __restrict__ plbuf){
  const int z = blockIdx.x, r = z>>2, d = threadIdx.x;
  const float v = pooled[z*1024+d];
  const float mean = blockRedSum(v) * (1.f/1024.f);
  const float df = v - mean;
  const float var = blockRedSum(df*df) * (1.f/1024.f);
  plbuf[z*1024+d] = df*rsqrtf(var+1e-5f)*pg[r*1024+d] + pb[r*1024+d];
}

// queries[z][:] += plbuf[z][k0..k0+32] @ pool_w[r][k0..k0+32][:]
// grid (z=12, kt=32), block 256: coalesced 1024-wide row reads, 4 d/thread.
__global__ __launch_bounds__(256)
void query_accum(const float* __restrict__ plbuf, const float* __restrict__ pw,
                 float* __restrict__ queries){
  const int z = blockIdx.x, r = z>>2, k0 = blockIdx.y*32;
  const int t = threadIdx.x;
  __shared__ float pls[32];
  if (t < 32) pls[t] = plbuf[z*1024 + k0 + t];
  __syncthreads();
  const float* wp = pw + (long long)r*1048576 + (long long)k0*1024;
  float acc[4] = {0.f,0.f,0.f,0.f};
  for (int s=0;s<32;s++){
    const float wv = pls[s];
    #pragma unroll
    for (int c=0;c<4;c++) acc[c] += wv*wp[s*1024 + t + c*256];
  }
  #pragma unroll
  for (int c=0;c<4;c++) atomicAdd(&queries[z*1024 + t + c*256], acc[c]);
}

// qpart[z][:] += queries[z][k0..k0+64] @ rel_w1[1024+k0..][:512]
// grid (z=12, kt=16), block 256: coalesced 512-wide rows, 2 n/thread.
__global__ __launch_bounds__(256)
void qpart_accum(const float* __restrict__ queries, const float* __restrict__ rw1,
                 float* __restrict__ qpart){
  const int z = blockIdx.x, k0 = blockIdx.y*64;
  const int t = threadIdx.x;
  __shared__ float qs[64];
  if (t < 64) qs[t] = queries[z*1024 + k0 + t];
  __syncthreads();
  const float* wp = rw1 + 1024*512 + (long long)k0*512;
  float acc[2] = {0.f,0.f};
  for (int s=0;s<64;s++){
    const float wv = qs[s];
    #pragma unroll
    for (int c=0;c<2;c++) acc[c] += wv*wp[s*512 + t + c*256];
  }
  #pragma unroll
  for (int c=0;c<2;c++) atomicAdd(&qpart[z*512 + t + c*256], acc[c]);
}

// rel = sigmoid(h @ rel_w2 + rel_b2), h fp32; one wave per row
__global__ void rel_score_f32(const float* __restrict__ h, const float* __restrict__ w2,
                              const float* __restrict__ b2p, float* __restrict__ relv){
  const int row = blockIdx.x*4 + (threadIdx.x>>6);
  const int lane = threadIdx.x & 63;
  const float* p = h + (long long)row*512;
  float a = 0.f;
  #pragma unroll
  for (int k=0;k<8;k++){ const int idx = lane + k*64; a += p[idx]*w2[idx]; }
  a = waveRedSum(a);
  if (lane==0){
    const float lg = a + b2p[0];
    relv[row] = 1.f/(1.f+expf(-lg));
  }
}

// ---------------- selection ----------------
__global__ __launch_bounds__(768)
void select_topk(const float* __restrict__ relv, int* __restrict__ selidx,
                 int* __restrict__ neff, int* __restrict__ anyv){
  const int b = blockIdx.x, c = threadIdx.x;
  __shared__ float rv[768];
  __shared__ int cnt;
  rv[c] = relv[(((c>>8)*4)+b)*256 + (c&255)];
  if (c==0) cnt = 0;
  __syncthreads();
  const float mine = rv[c];
  const bool valid = (mine >= 0.5f);
  int rank = 0;
  for (int j=0;j<768;j++){
    const float vj = rv[j];
    if (vj >= 0.5f && (vj > mine || (vj == mine && j < c))) rank++;
  }
  if (valid && rank < 256){
    const int s = atomicAdd(&cnt, 1);
    selidx[b*256 + s] = c;
  }
  __syncthreads();
  if (c==0){ neff[b] = cnt; anyv[b] = (cnt>0) ? 1 : 0; }
}

__global__ void gather_sel(const u16* __restrict__ rb16, const int* __restrict__ selidx,
                           const int* __restrict__ neff, u16* __restrict__ seltok){
  const int slot = blockIdx.x, b = blockIdx.y, tid = threadIdx.x;
  uint2 val; val.x=0u; val.y=0u;
  if (slot < neff[b]){
    const int c = selidx[b*256+slot];
    const uint2* src = (const uint2*)(rb16 + (long long)(((c>>8)*4+b)*256 + (c&255))*1024);
    val = src[tid];
  }
  ((uint2*)(seltok + (long long)(b*256+slot)*1024))[tid] = val;
}

// masked softmax over key slots (one wave per row of 256)
__global__ void attn_softmax(u16* __restrict__ S, const int* __restrict__ neff){
  const int ri = blockIdx.x*4 + (threadIdx.x>>6);
  const int lane = threadIdx.x & 63;
  const int b = ri >> 14;
  const int ne = neff[b];
  u16* p = S + (long long)ri*256 + lane*4;
  if (ne == 0){ uint2 zz; zz.x=0u; zz.y=0u; *(uint2*)p = zz; return; }
  uint2 raw = *(const uint2*)p;
  u16 uu[4] = {(u16)(raw.x&0xffffu),(u16)(raw.x>>16),(u16)(raw.y&0xffffu),(u16)(raw.y>>16)};
  float xs[4];
  #pragma unroll
  for (int q2=0;q2<4;q2++){ const int tt = lane*4+q2; xs[q2] = (tt<ne)? b2f(uu[q2]) : -1e30f; }
  float mx = fmaxf(fmaxf(xs[0],xs[1]),fmaxf(xs[2],xs[3]));
  mx = waveRedMax(mx);
  float e[4]; float sm=0.f;
  #pragma unroll
  for (int q2=0;q2<4;q2++){ e[q2] = (lane*4+q2<ne)? expf(xs[q2]-mx) : 0.f; sm += e[q2]; }
  sm = waveRedSum(sm);
  const float inv = 1.f/sm;
  #pragma unroll
  for (int q2=0;q2<4;q2++) uu[q2] = f2b(e[q2]*inv);
  raw.x = (u32)uu[0] | ((u32)uu[1]<<16);
  raw.y = (u32)uu[2] | ((u32)uu[3]<<16);
  *(uint2*)p = raw;
}

// residual + LayerNorm + any_valid select
__global__ void final_ln(const float* __restrict__ x, const u16* __restrict__ fused,
                         const float* __restrict__ g, const float* __restrict__ bb,
                         const int* __restrict__ anyv, float* __restrict__ out){
  const int row = blockIdx.x; const int b = row>>11; const int tid = threadIdx.x;
  const float4 xv = ((const float4*)(x + (long long)row*1024))[tid];
  const uint2 fv = ((const uint2*)(fused + (long long)row*1024))[tid];
  const float e0 = xv.x + b2f((u16)(fv.x&0xffffu));
  const float e1 = xv.y + b2f((u16)(fv.x>>16));
  const float e2 = xv.z + b2f((u16)(fv.y&0xffffu));
  const float e3 = xv.w + b2f((u16)(fv.y>>16));
  const float mean = blockRedSum(e0+e1+e2+e3) * (1.f/1024.f);
  const float d0=e0-mean, d1=e1-mean, d2=e2-mean, d3=e3-mean;
  const float var = blockRedSum(d0*d0+d1*d1+d2*d2+d3*d3) * (1.f/1024.f);
  const float inv = rsqrtf(var + 1e-5f);
  const float4 gv = ((const float4*)g)[tid];
  const float4 bv = ((const float4*)bb)[tid];
  float4 o;
  if (anyv[b]){
    o.x = d0*inv*gv.x + bv.x; o.y = d1*inv*gv.y + bv.y;
    o.z = d2*inv*gv.z + bv.z; o.w = d3*inv*gv.w + bv.w;
  } else o = xv;
  ((float4*)(out + (long long)row*1024))[tid] = o;
}

// ============================================================================
extern "C" void kernel_launch(void* const* d_in, const int* in_sizes, int n_in,
                              void* d_out, int out_size, void* d_ws, size_t ws_size,
                              hipStream_t stream) {
  (void)in_sizes; (void)n_in;
  const float* x      = (const float*)d_in[0];
  const float* retr   = (const float*)d_in[1];
  const float* qg_w1  = (const float*)d_in[2];
  const float* qg_b1  = (const float*)d_in[3];
  const float* qg_w2  = (const float*)d_in[4];
  const float* qg_b2  = (const float*)d_in[5];
  const float* pln_g  = (const float*)d_in[6];
  const float* pln_b  = (const float*)d_in[7];
  const float* pool_w = (const float*)d_in[8];
  const float* pool_b = (const float*)d_in[9];
  const float* rel_w1 = (const float*)d_in[10];
  const float* rel_b1 = (const float*)d_in[11];
  const float* rel_w2 = (const float*)d_in[12];
  const float* rel_b2 = (const float*)d_in[13];
  const float* in_w   = (const float*)d_in[14];
  const float* in_b   = (const float*)d_in[15];
  const float* out_w  = (const float*)d_in[16];
  const float* out_b  = (const float*)d_in[17];
  const float* fln_g  = (const float*)d_in[18];
  const float* fln_b  = (const float*)d_in[19];
  float* out = (float*)d_out;
  char* ws = (char*)d_ws;

  const size_t MB = 1u<<20;
  const size_t REQUIRED = 131*MB;
  if (ws_size < REQUIRED){
    ws_report<<<(out_size/4 + 255)/256, 256, 0, stream>>>(out, out_size/4, (float)(ws_size>>20));
    return;
  }

  // ---- layout (MB offsets; lifetimes commented) ----
  u16* qg1Th = (u16*)(ws + 0*MB);    // 6   [A]
  u16* qg1Tl = (u16*)(ws + 6*MB);    // 6   [A]
  u16* qg2Th = (u16*)(ws + 12*MB);   // 6   [A]
  u16* qg2Tl = (u16*)(ws + 18*MB);   // 6   [A]
  u16* xh    = (u16*)(ws + 24*MB);   // 16  [A, F]  (= bf16(x))
  u16* xl    = (u16*)(ws + 40*MB);   // 16  [A]
  u16* rh    = (u16*)(ws + 56*MB);   // 6   [D, E]  (= bf16(retr))
  u16* rl    = (u16*)(ws + 62*MB);   // 6   [D]
  u16* relTh = (u16*)(ws + 68*MB);   // 1   [D]
  u16* relTl = (u16*)(ws + 69*MB);   // 1   [D]
  u16* qfh   = (u16*)(ws + 70*MB);   // 16  [A->B] per retriever
  u16* qfl   = (u16*)(ws + 86*MB);   // 16  [A->B]
  // region 102..118: t1h/t1l (A) | scores fp32 (B) | hbuf (D) | attnout (F)
  u16*   t1h    = (u16*)(ws + 102*MB);  // 8
  u16*   t1l    = (u16*)(ws + 110*MB);  // 8
  float* scores = (float*)(ws + 102*MB);// 16
  float* hbuf   = (float*)(ws + 102*MB);// 6
  u16*   attnout= (u16*)(ws + 102*MB);  // 16
  // stage F reuse of dead zones (each 2 MB):
  u16* qbuf   = (u16*)(ws + 0*MB);    // 16 (over qg1T/qg2T, dead after A)
  u16* fused  = (u16*)(ws + 0*MB);    // 16 (over qbuf, dead after QK^T)
  u16* inT    = (u16*)(ws + 40*MB);   // 6  (over xl, dead after A)
  u16* outT   = (u16*)(ws + 46*MB);   // 2
  u16* seltok = (u16*)(ws + 48*MB);   // 2  [4][256][1024] bf16
  u16* kbuf   = (u16*)(ws + 50*MB);   // 2
  u16* VT     = (u16*)(ws + 52*MB);   // 2  (54..56 spare)
  u16* Sattn  = (u16*)(ws + 70*MB);   // 32 (over qfh/qfl, dead after pooling)
  // smalls at 118..
  char* SM = ws + 118*MB;
  float* wbuf    = (float*)(SM);            // 96 KB [12][2048]
  float* pooledB = (float*)(SM + 98304);    // 48 KB [12][1024]
  float* plbuf   = (float*)(SM + 147456);   // 48 KB [12][1024]
  float* queries = (float*)(SM + 196608);   // 48 KB
  float* qpart   = (float*)(SM + 245760);   // 24 KB
  float* relv    = (float*)(SM + 270336);   // 12 KB
  int*   selidx  = (int*)(SM + 282624);     //  4 KB
  int*   neff    = (int*)(SM + 286720);
  int*   anyv    = (int*)(SM + 286784);
  float* mrow    = (float*)(SM + 286848);   //  8 KB [2048]
  float* drow    = (float*)(SM + 295040);   //  8 KB

  dim3 b256(256);
  dim3 tb(32,8);

  // --- prep: split weights/activations ---
  split_transpose_w<<<dim3(32,32,3), tb, 0, stream>>>(qg_w1, qg1Th, qg1Tl, 1024, 1024);
  split_transpose_w<<<dim3(32,32,3), tb, 0, stream>>>(qg_w2, qg2Th, qg2Tl, 1024, 1024);
  split_transpose_w<<<dim3(16,32,1), tb, 0, stream>>>(rel_w1, relTh, relTl, 1024, 512);
  split_f32_k<<<8192, b256, 0, stream>>>(x,    xh, xl, 2097152);
  split_f32_k<<<3072, b256, 0, stream>>>(retr, rh, rl,  786432);
  zero_f32<<<144, b256, 0, stream>>>(wbuf, 36864);   // wbuf[24576] + pooledB[12288]

  // --- stages A+B per retriever (split precision) ---
  for (int r = 0; r < 3; r++){
    const long long wo = (long long)r*1048576;
    for (int hf = 0; hf < 2; hf++){
      const long long xo = (long long)hf*4194304;   // 4096 rows * 1024
      gemm_nt_split<SP_GELU_SPLIT><<<dim3(8,32), b256, 0, stream>>>(
          xh+xo, xl+xo, 1024,  qg1Th+wo, qg1Tl+wo, 1024,
          t1h, t1l, 1024,  qg_b1+r*1024, 1.f, 1024);
      gemm_nt_split<SP_BIAS_SPLIT><<<dim3(8,32), b256, 0, stream>>>(
          t1h, t1l, 1024,  qg2Th+wo, qg2Tl+wo, 1024,
          qfh+xo, qfl+xo, 1024,  qg_b2+r*1024, 1.f, 1024);
    }
    for (int b = 0; b < 4; b++){
      const long long qo = (long long)b*2097152;
      gemm_nt_split<SP_SCALE_F32><<<dim3(16,16), b256, 0, stream>>>(
          qfh+qo, qfl+qo, 1024,  qfh+qo, qfl+qo, 1024,
          scores, nullptr, 2048,  nullptr, 0.03125f, 1024);
      row_stats_f32<<<2048, b256, 0, stream>>>(scores, mrow, drow);
      col_mean_f32<<<dim3(8,32), b256, 0, stream>>>(scores, mrow, drow, wbuf + (r*4+b)*2048);
    }
    pooled_par<<<dim3(4,16), b256, 0, stream>>>(qfh, qfl, wbuf + r*8192, pooledB + r*4096);
  }
  pool_ln<<<12, 1024, 0, stream>>>(pooledB, pln_g, pln_b, plbuf);
  init_queries<<<48, b256, 0, stream>>>(pool_b, queries);
  query_accum<<<dim3(12,32), b256, 0, stream>>>(plbuf, pool_w, queries);

  // --- stage D: relevance scorer (split GEMM, fp32 h) ---
  init_qpart<<<24, b256, 0, stream>>>(rel_b1, qpart);
  qpart_accum<<<dim3(12,16), b256, 0, stream>>>(queries, rel_w1, qpart);
  gemm_nt_split<SP_QBG_F32><<<dim3(4,24), b256, 0, stream>>>(
      rh, rl, 1024,  relTh, relTl, 1024,  hbuf, nullptr, 512,  qpart, 1.f, 1024);
  rel_score_f32<<<768, b256, 0, stream>>>(hbuf, rel_w2, rel_b2, relv);

  // --- stage E: selection ---
  select_topk<<<4, 768, 0, stream>>>(relv, selidx, neff, anyv);
  gather_sel<<<dim3(256,4), b256, 0, stream>>>(rh, selidx, neff, seltok);

  // --- stage F: fusion cross-attention (plain bf16) ---
  transpose_w<<<dim3(32,32,3), tb, 0, stream>>>(in_w,  inT,  1024, 1024);
  transpose_w<<<dim3(32,32,1), tb, 0, stream>>>(out_w, outT, 1024, 1024);
  gemm_nt<EPI_BIAS><<<dim3(8,64,1), b256, 0, stream>>>(
      xh,1024,0,0,  inT,1024,0,0,  qbuf,1024,0,0,  in_b,0, 1.f, 1024, 1);
  gemm_nt<EPI_BIAS><<<dim3(8,8,1), b256, 0, stream>>>(
      seltok,1024,0,0,  inT+1048576,1024,0,0,  kbuf,1024,0,0,  in_b+1024,0, 1.f, 1024, 1);
  gemm_nt<EPI_VT><<<dim3(8,8,1), b256, 0, stream>>>(
      seltok,1024,0,0,  inT+2097152,1024,0,0,  VT,0,0,0,  in_b+2048,0, 1.f, 1024, 1);
  gemm_nt<EPI_SCALE><<<dim3(2,16,32), b256, 0, stream>>>(
      qbuf,1024,2097152,128,  kbuf,1024,262144,128,  Sattn,256,4194304,524288,
      (const float*)nullptr,0, 0.08838834764831845f, 128, 8);
  attn_softmax<<<16384, b256, 0, stream>>>(Sattn, neff);
  gemm_nt<EPI_NONE><<<dim3(1,16,32), b256, 0, stream>>>(
      Sattn,256,4194304,524288,  VT,256,262144,32768,  attnout,1024,2097152,128,
      (const float*)nullptr,0, 1.f, 256, 8);
  gemm_nt<EPI_BIAS><<<dim3(8,64,1), b256, 0, stream>>>(
      attnout,1024,0,0,  outT,1024,0,0,  fused,1024,0,0,  out_b,0, 1.f, 1024, 1);
  final_ln<<<8192, b256, 0, stream>>>(x, fused, fln_g, fln_b, anyv, out);
}

// Round 9
// 1712.566 us; speedup vs baseline: 1.5500x; 1.0679x over previous
//
#include <hip/hip_runtime.h>
#include <math.h>

// ============================================================================
// RetrievalAugmentedProcessor — MI355X (gfx950)
// B=4 S=2048 D=1024 R=3 K=256 MAXR=256 H=8 HD=128
// R9: R7/R8 failed with IDENTICAL absmax 1.8352 -> orchestration bug, not
//     global_load_lds. Root cause: R7 stored qf for all 3 retrievers into a
//     16MB (one-retriever) slot -> r=1 clobbered qfl, r=2 clobbered t1/scores.
//     Fix: per-retriever qf reuse (R6 interleaved loop) + repacked layout so
//     z=2 score batching fits per-retriever. global_load_lds REINSTATED
//     (R7==R8 absmax proves it was byte-correct).
// Layout (MB):  0..24 qgT[A] | 24..40 xh[A,F] | 40..56 xl[A] | 56..72 qfh(r)
//   | 72..88 qfl(r) | 88..104 t1[A]/scoresA[B]/hbuf[D]/Sattn lo[F]
//   | 104..120 scoresB[B]/Sattn hi[F] | 120.. smalls
// Overlays: rh@0 rl@6 relT@12 seltok@14 kbuf@16 VT@18 [D/E] (over dead qgT);
//   inT@40 outT@46 qbuf@56 fused@72 attnout@0 [F]. Peak 120MB <= 131.
// ============================================================================

typedef unsigned short u16;
typedef unsigned int   u32;
typedef __attribute__((ext_vector_type(8))) short short8;   // 8 bf16
typedef __attribute__((ext_vector_type(4))) float f32x4;    // MFMA acc
typedef __attribute__((ext_vector_type(4))) u16  u16x4;

__device__ __forceinline__ float b2f(u16 u){ union{float f;u32 i;} x; x.i=((u32)u)<<16; return x.f; }
__device__ __forceinline__ u16 f2b(float f){ union{float f;u32 i;} x; x.f=f; u32 r=x.i+0x7fffu+((x.i>>16)&1u); return (u16)(r>>16); }
__device__ __forceinline__ float gelu_f(float v){ return 0.5f*v*(1.f+erff(v*0.70710678118654752f)); }

__device__ __forceinline__ void load_lds16(const u16* g, u16* l){
  __builtin_amdgcn_global_load_lds((const __attribute__((address_space(1))) u32*)g,
                                   (__attribute__((address_space(3))) u32*)l, 16, 0, 0);
}

// ---------------- reductions ----------------
__device__ __forceinline__ float waveRedSum(float v){
  #pragma unroll
  for (int o=32;o>0;o>>=1) v += __shfl_xor(v,o);
  return v;
}
__device__ __forceinline__ float waveRedMax(float v){
  #pragma unroll
  for (int o=32;o>0;o>>=1) v = fmaxf(v, __shfl_xor(v,o));
  return v;
}
__device__ float blockRedSum(float v){
  __shared__ float tmp[17];
  const int lane = threadIdx.x&63, wv = threadIdx.x>>6, nw = blockDim.x>>6;
  v = waveRedSum(v);
  __syncthreads();
  if (lane==0) tmp[wv]=v;
  __syncthreads();
  if (threadIdx.x==0){ float s=tmp[0]; for(int i=1;i<nw;i++) s+=tmp[i]; tmp[16]=s; }
  __syncthreads();
  return tmp[16];
}
__device__ float blockRedMax(float v){
  __shared__ float tmp[17];
  const int lane = threadIdx.x&63, wv = threadIdx.x>>6, nw = blockDim.x>>6;
  v = waveRedMax(v);
  __syncthreads();
  if (lane==0) tmp[wv]=v;
  __syncthreads();
  if (threadIdx.x==0){ float s=tmp[0]; for(int i=1;i<nw;i++) s=fmaxf(s,tmp[i]); tmp[16]=s; }
  __syncthreads();
  return tmp[16];
}

// ============================================================================
// Plain bf16 NT GEMM (stage F), global_load_lds staging.
enum { EPI_NONE=0, EPI_BIAS=1, EPI_SCALE=3, EPI_VT=5 };

template<int EPI>
__global__ __launch_bounds__(256,2)
void gemm_nt(const u16* __restrict__ Ag, long long lda, long long sA1, long long sA2,
             const u16* __restrict__ Bg, long long ldb, long long sB1, long long sB2,
             u16* __restrict__ Cg, long long ldc, long long sC1, long long sC2,
             const float* __restrict__ bias, long long sBias,
             float scale, int K, int H)
{
  __shared__ u16 As[128*32];
  __shared__ u16 Bs[128*32];
  const int z  = blockIdx.z;
  const int zb = z / H, zh = z - zb*H;
  const u16* A = Ag + zb*sA1 + zh*sA2;
  const u16* B = Bg + zb*sB1 + zh*sB2;
  const int m0 = blockIdx.y*128, n0 = blockIdx.x*128;
  const int t  = threadIdx.x;
  const int lane = t & 63, wv = t >> 6;
  const int wm = (wv>>1)*64, wn = (wv&1)*64;

  const u16* ga0 = A + (long long)(m0 + (t>>2))*lda + (t&3)*8;
  const u16* ga1 = ga0 + 64*lda;
  const u16* gb0 = B + (long long)(n0 + (t>>2))*ldb + (t&3)*8;
  const u16* gb1 = gb0 + 64*ldb;
  u16* lA0 = As + t*8;  u16* lA1 = As + 2048 + t*8;
  u16* lB0 = Bs + t*8;  u16* lB1 = Bs + 2048 + t*8;

  f32x4 acc[4][4];
  #pragma unroll
  for (int i=0;i<4;i++)
    #pragma unroll
    for (int j=0;j<4;j++) acc[i][j] = (f32x4){0.f,0.f,0.f,0.f};

  const short8* arp = (const short8*)(As + (wm + (lane&15))*32 + ((lane>>4)*8));
  const short8* brp = (const short8*)(Bs + (wn + (lane&15))*32 + ((lane>>4)*8));

  for (int kk = 0; kk < K; kk += 32) {
    load_lds16(ga0, lA0); load_lds16(ga1, lA1);
    load_lds16(gb0, lB0); load_lds16(gb1, lB1);
    ga0 += 32; ga1 += 32; gb0 += 32; gb1 += 32;
    __syncthreads();
    short8 af[4], bfr[4];
    #pragma unroll
    for (int i=0;i<4;i++) af[i]  = arp[i*64];
    #pragma unroll
    for (int j=0;j<4;j++) bfr[j] = brp[j*64];
    #pragma unroll
    for (int i=0;i<4;i++)
      #pragma unroll
      for (int j=0;j<4;j++)
        acc[i][j] = __builtin_amdgcn_mfma_f32_16x16x32_bf16(af[i], bfr[j], acc[i][j], 0, 0, 0);
    __syncthreads();
  }

  u16* C = Cg + zb*sC1 + zh*sC2;
  const float* bz = bias + zb*sBias;
  const int rb0 = m0 + wm + ((lane>>4)<<2);
  const int cb0 = n0 + wn + (lane&15);
  #pragma unroll
  for (int j=0;j<4;j++){
    const int cn = cb0 + j*16;
    float bv = 0.f;
    if constexpr (EPI==EPI_BIAS || EPI==EPI_VT) bv = bz[cn];
    #pragma unroll
    for (int i=0;i<4;i++){
      #pragma unroll
      for (int p=0;p<4;p++){
        const int row = rb0 + i*16 + p;
        float v = acc[i][j][p];
        if constexpr (EPI==EPI_SCALE) v *= scale;
        if constexpr (EPI==EPI_BIAS)  v += bv;
        if constexpr (EPI==EPI_VT) {
          v += bv;
          const int bb = row>>8, tt = row&255, hh = cn>>7, dd = cn&127;
          C[((long long)((bb*8+hh)*128+dd)<<8) + tt] = f2b(v);
        } else {
          C[(long long)row*ldc + cn] = f2b(v);
        }
      }
    }
  }
}

// ============================================================================
// Split-bf16 NT GEMM: acc += Al*Bh + Ah*Bl + Ah*Bh. global_load_lds staging.
// z-batched: A/B/C advance by sAz/sBz/sCz elements per blockIdx.z.
enum { SP_GELU_SPLIT=0, SP_BIAS_SPLIT=1, SP_SCALE_F32=2, SP_QBG_F32=3 };

template<int EPI>
__global__ __launch_bounds__(256,2)
void gemm_nt_split(const u16* __restrict__ Ah_, const u16* __restrict__ Al_, long long lda, long long sAz,
                   const u16* __restrict__ Bh_, const u16* __restrict__ Bl_, long long ldb, long long sBz,
                   void* __restrict__ C0, void* __restrict__ C1, long long ldc, long long sCz,
                   const float* __restrict__ bias, float scale, int K)
{
  __shared__ u16 AsH[128*32];
  __shared__ u16 AsL[128*32];
  __shared__ u16 BsH[128*32];
  __shared__ u16 BsL[128*32];
  const int z = blockIdx.z;
  const int m0 = blockIdx.y*128, n0 = blockIdx.x*128;
  const int t  = threadIdx.x;
  const int lane = t & 63, wv = t >> 6;
  const int wm = (wv>>1)*64, wn = (wv&1)*64;

  const long long arow = (long long)z*sAz + (long long)(m0 + (t>>2))*lda + (t&3)*8;
  const long long brow = (long long)z*sBz + (long long)(n0 + (t>>2))*ldb + (t&3)*8;
  const u16* gah0 = Ah_ + arow;  const u16* gah1 = gah0 + 64*lda;
  const u16* gal0 = Al_ + arow;  const u16* gal1 = gal0 + 64*lda;
  const u16* gbh0 = Bh_ + brow;  const u16* gbh1 = gbh0 + 64*ldb;
  const u16* gbl0 = Bl_ + brow;  const u16* gbl1 = gbl0 + 64*ldb;
  u16* lAh0 = AsH + t*8;  u16* lAh1 = AsH + 2048 + t*8;
  u16* lAl0 = AsL + t*8;  u16* lAl1 = AsL + 2048 + t*8;
  u16* lBh0 = BsH + t*8;  u16* lBh1 = BsH + 2048 + t*8;
  u16* lBl0 = BsL + t*8;  u16* lBl1 = BsL + 2048 + t*8;

  f32x4 acc[4][4];
  #pragma unroll
  for (int i=0;i<4;i++)
    #pragma unroll
    for (int j=0;j<4;j++) acc[i][j] = (f32x4){0.f,0.f,0.f,0.f};

  const int foff = (lane&15)*32 + ((lane>>4)*8);
  const short8* arh = (const short8*)(AsH + wm*32 + foff);
  const short8* arl = (const short8*)(AsL + wm*32 + foff);
  const short8* brh = (const short8*)(BsH + wn*32 + foff);
  const short8* brl = (const short8*)(BsL + wn*32 + foff);

  for (int kk = 0; kk < K; kk += 32) {
    load_lds16(gah0, lAh0); load_lds16(gah1, lAh1);
    load_lds16(gal0, lAl0); load_lds16(gal1, lAl1);
    load_lds16(gbh0, lBh0); load_lds16(gbh1, lBh1);
    load_lds16(gbl0, lBl0); load_lds16(gbl1, lBl1);
    gah0 += 32; gah1 += 32; gal0 += 32; gal1 += 32;
    gbh0 += 32; gbh1 += 32; gbl0 += 32; gbl1 += 32;
    __syncthreads();
    short8 fah[4], fal[4], fbh[4], fbl[4];
    #pragma unroll
    for (int i=0;i<4;i++){ fah[i]=arh[i*64]; fal[i]=arl[i*64]; }
    #pragma unroll
    for (int j=0;j<4;j++){ fbh[j]=brh[j*64]; fbl[j]=brl[j*64]; }
    #pragma unroll
    for (int i=0;i<4;i++)
      #pragma unroll
      for (int j=0;j<4;j++){
        acc[i][j] = __builtin_amdgcn_mfma_f32_16x16x32_bf16(fal[i], fbh[j], acc[i][j], 0, 0, 0);
        acc[i][j] = __builtin_amdgcn_mfma_f32_16x16x32_bf16(fah[i], fbl[j], acc[i][j], 0, 0, 0);
        acc[i][j] = __builtin_amdgcn_mfma_f32_16x16x32_bf16(fah[i], fbh[j], acc[i][j], 0, 0, 0);
      }
    __syncthreads();
  }

  const int rb0 = m0 + wm + ((lane>>4)<<2);
  const int cb0 = n0 + wn + (lane&15);
  #pragma unroll
  for (int j=0;j<4;j++){
    const int cn = cb0 + j*16;
    float bv = 0.f;
    if constexpr (EPI==SP_GELU_SPLIT || EPI==SP_BIAS_SPLIT) bv = bias[cn];
    #pragma unroll
    for (int i=0;i<4;i++){
      #pragma unroll
      for (int p=0;p<4;p++){
        const int row = rb0 + i*16 + p;
        float v = acc[i][j][p];
        const long long o = (long long)z*sCz + (long long)row*ldc + cn;
        if constexpr (EPI==SP_GELU_SPLIT || EPI==SP_BIAS_SPLIT){
          v += bv;
          if constexpr (EPI==SP_GELU_SPLIT) v = gelu_f(v);
          const u16 h = f2b(v);
          ((u16*)C0)[o] = h;
          ((u16*)C1)[o] = f2b(v - b2f(h));
        }
        if constexpr (EPI==SP_SCALE_F32) ((float*)C0)[o] = v*scale;
        if constexpr (EPI==SP_QBG_F32)   ((float*)C0)[o] = gelu_f(v + bias[(row>>8)*512 + cn]);
      }
    }
  }
}

// ---------------- prep kernels ----------------
__global__ void transpose_w(const float* __restrict__ in, u16* __restrict__ out, int rows, int cols){
  __shared__ float tl[32][33];
  const long long zo = (long long)blockIdx.z*rows*cols;
  const int c0 = blockIdx.x*32, r0 = blockIdx.y*32;
  const int tx = threadIdx.x, ty = threadIdx.y;
  #pragma unroll
  for (int yy=ty; yy<32; yy+=8) tl[yy][tx] = in[zo + (long long)(r0+yy)*cols + (c0+tx)];
  __syncthreads();
  #pragma unroll
  for (int yy=ty; yy<32; yy+=8) out[zo + (long long)(c0+yy)*rows + (r0+tx)] = f2b(tl[tx][yy]);
}

__global__ void split_transpose_w(const float* __restrict__ in, u16* __restrict__ outH,
                                  u16* __restrict__ outL, int rows, int cols){
  __shared__ float tl[32][33];
  const long long zo = (long long)blockIdx.z*rows*cols;
  const int c0 = blockIdx.x*32, r0 = blockIdx.y*32;
  const int tx = threadIdx.x, ty = threadIdx.y;
  #pragma unroll
  for (int yy=ty; yy<32; yy+=8) tl[yy][tx] = in[zo + (long long)(r0+yy)*cols + (c0+tx)];
  __syncthreads();
  #pragma unroll
  for (int yy=ty; yy<32; yy+=8){
    const float v = tl[tx][yy];
    const u16 h = f2b(v);
    const long long o = zo + (long long)(c0+yy)*rows + (r0+tx);
    outH[o] = h;
    outL[o] = f2b(v - b2f(h));
  }
}

__global__ void split_f32_k(const float* __restrict__ in, u16* __restrict__ oh,
                            u16* __restrict__ ol, int n4){
  const int i = blockIdx.x*256 + threadIdx.x;
  if (i < n4){
    const float4 v = ((const float4*)in)[i];
    u16x4 hh, ll;
    hh.x=f2b(v.x); ll.x=f2b(v.x-b2f(hh.x));
    hh.y=f2b(v.y); ll.y=f2b(v.y-b2f(hh.y));
    hh.z=f2b(v.z); ll.z=f2b(v.z-b2f(hh.z));
    hh.w=f2b(v.w); ll.w=f2b(v.w-b2f(hh.w));
    ((u16x4*)oh)[i] = hh;
    ((u16x4*)ol)[i] = ll;
  }
}

__global__ void zero_f32(float* __restrict__ p, int n){
  const int i = blockIdx.x*256 + threadIdx.x;
  if (i < n) p[i] = 0.f;
}

__global__ void init_queries(const float* __restrict__ pb, float* __restrict__ q){
  const int i = blockIdx.x*256 + threadIdx.x;
  if (i < 12288) q[i] = pb[(i>>12)*1024 + (i&1023)];
}
__global__ void init_qpart(const float* __restrict__ rb1, float* __restrict__ qp){
  const int i = blockIdx.x*256 + threadIdx.x;
  if (i < 6144) qp[i] = rb1[i&511];
}

__global__ void ws_report(float* __restrict__ out, int n4, float val){
  const int i = blockIdx.x*256 + threadIdx.x;
  if (i < n4){
    float4 z; z.x = (i==0)? val : 0.f; z.y=0.f; z.z=0.f; z.w=0.f;
    ((float4*)out)[i] = z;
  }
}

// ---------------- pooling (fp32 scores) ----------------
__global__ void row_stats_f32(const float* __restrict__ S, float* __restrict__ mOut,
                              float* __restrict__ dOut){
  const int row = blockIdx.x;
  const float4* p = (const float4*)(S + (long long)row*2048);
  const int tid = threadIdx.x;
  const float4 a = p[2*tid], b = p[2*tid+1];
  float v[8] = {a.x,a.y,a.z,a.w,b.x,b.y,b.z,b.w};
  float mx = v[0];
  #pragma unroll
  for (int k=1;k<8;k++) mx = fmaxf(mx, v[k]);
  mx = blockRedMax(mx);
  float s = 0.f;
  #pragma unroll
  for (int k=0;k<8;k++) s += expf(v[k]-mx);
  s = blockRedSum(s);
  if (tid==0){ mOut[row]=mx; dOut[row]=s; }
}

__global__ void col_mean_f32(const float* __restrict__ S, const float* __restrict__ m,
                             const float* __restrict__ den, float* __restrict__ w){
  const int tc = blockIdx.x*256 + threadIdx.x;
  const int s0 = blockIdx.y*64;
  const float* p = S + (long long)s0*2048 + tc;
  float acc = 0.f;
  for (int s=0;s<64;s++)
    acc += expf(p[(long long)s<<11] - m[s0+s]) * (1.0f/den[s0+s]);
  atomicAdd(&w[tc], acc * (1.f/2048.f));
}

// pooled[b][d] += tile sums; grid (4,16) per retriever (R6-proven)
__global__ __launch_bounds__(256)
void pooled_par(const u16* __restrict__ qfh, const u16* __restrict__ qfl,
                const float* __restrict__ w, float* __restrict__ pooled){
  const int b = blockIdx.x, tt0 = blockIdx.y*128;
  const int t = threadIdx.x;
  __shared__ float wsh[128];
  if (t < 128) wsh[t] = w[b*2048 + tt0 + t];
  __syncthreads();
  const long long base = (long long)b*2097152 + (long long)tt0*1024;
  const u16* ph = qfh + base;
  const u16* pl = qfl + base;
  float acc[4] = {0.f,0.f,0.f,0.f};
  for (int s=0; s<128; s++){
    const float wt = wsh[s];
    const long long o = (long long)s*1024;
    #pragma unroll
    for (int k=0;k<4;k++){
      const int dd = t + k*256;
      acc[k] += wt*(b2f(ph[o+dd]) + b2f(pl[o+dd]));
    }
  }
  #pragma unroll
  for (int k=0;k<4;k++) atomicAdd(&pooled[b*1024 + t + k*256], acc[k]);
}

__global__ __launch_bounds__(1024)
void pool_ln(const float* __restrict__ pooled, const float* __restrict__ pg,
             const float* __restrict__ pb, float* __restrict__ plbuf){
  const int z = blockIdx.x, r = z>>2, d = threadIdx.x;
  const float v = pooled[z*1024+d];
  const float mean = blockRedSum(v) * (1.f/1024.f);
  const float df = v - mean;
  const float var = blockRedSum(df*df) * (1.f/1024.f);
  plbuf[z*1024+d] = df*rsqrtf(var+1e-5f)*pg[r*1024+d] + pb[r*1024+d];
}

__global__ __launch_bounds__(256)
void query_accum(const float* __restrict__ plbuf, const float* __restrict__ pw,
                 float* __restrict__ queries){
  const int z = blockIdx.x, r = z>>2, k0 = blockIdx.y*32;
  const int t = threadIdx.x;
  __shared__ float pls[32];
  if (t < 32) pls[t] = plbuf[z*1024 + k0 + t];
  __syncthreads();
  const float* wp = pw + (long long)r*1048576 + (long long)k0*1024;
  float acc[4] = {0.f,0.f,0.f,0.f};
  for (int s=0;s<32;s++){
    const float wv = pls[s];
    #pragma unroll
    for (int c=0;c<4;c++) acc[c] += wv*wp[s*1024 + t + c*256];
  }
  #pragma unroll
  for (int c=0;c<4;c++) atomicAdd(&queries[z*1024 + t + c*256], acc[c]);
}

__global__ __launch_bounds__(256)
void qpart_accum(const float* __restrict__ queries, const float* __restrict__ rw1,
                 float* __restrict__ qpart){
  const int z = blockIdx.x, k0 = blockIdx.y*64;
  const int t = threadIdx.x;
  __shared__ float qs[64];
  if (t < 64) qs[t] = queries[z*1024 + k0 + t];
  __syncthreads();
  const float* wp = rw1 + 1024*512 + (long long)k0*512;
  float acc[2] = {0.f,0.f};
  for (int s=0;s<64;s++){
    const float wv = qs[s];
    #pragma unroll
    for (int c=0;c<2;c++) acc[c] += wv*wp[s*512 + t + c*256];
  }
  #pragma unroll
  for (int c=0;c<2;c++) atomicAdd(&qpart[z*512 + t + c*256], acc[c]);
}

__global__ void rel_score_f32(const float* __restrict__ h, const float* __restrict__ w2,
                              const float* __restrict__ b2p, float* __restrict__ relv){
  const int row = blockIdx.x*4 + (threadIdx.x>>6);
  const int lane = threadIdx.x & 63;
  const float* p = h + (long long)row*512;
  float a = 0.f;
  #pragma unroll
  for (int k=0;k<8;k++){ const int idx = lane + k*64; a += p[idx]*w2[idx]; }
  a = waveRedSum(a);
  if (lane==0){
    const float lg = a + b2p[0];
    relv[row] = 1.f/(1.f+expf(-lg));
  }
}

// ---------------- selection ----------------
__global__ __launch_bounds__(768)
void select_topk(const float* __restrict__ relv, int* __restrict__ selidx,
                 int* __restrict__ neff, int* __restrict__ anyv){
  const int b = blockIdx.x, c = threadIdx.x;
  __shared__ float rv[768];
  __shared__ int cnt;
  rv[c] = relv[(((c>>8)*4)+b)*256 + (c&255)];
  if (c==0) cnt = 0;
  __syncthreads();
  const float mine = rv[c];
  const bool valid = (mine >= 0.5f);
  int rank = 0;
  for (int j=0;j<768;j++){
    const float vj = rv[j];
    if (vj >= 0.5f && (vj > mine || (vj == mine && j < c))) rank++;
  }
  if (valid && rank < 256){
    const int s = atomicAdd(&cnt, 1);
    selidx[b*256 + s] = c;
  }
  __syncthreads();
  if (c==0){ neff[b] = cnt; anyv[b] = (cnt>0) ? 1 : 0; }
}

__global__ void gather_sel(const u16* __restrict__ rb16, const int* __restrict__ selidx,
                           const int* __restrict__ neff, u16* __restrict__ seltok){
  const int slot = blockIdx.x, b = blockIdx.y, tid = threadIdx.x;
  uint2 val; val.x=0u; val.y=0u;
  if (slot < neff[b]){
    const int c = selidx[b*256+slot];
    const uint2* src = (const uint2*)(rb16 + (long long)(((c>>8)*4+b)*256 + (c&255))*1024);
    val = src[tid];
  }
  ((uint2*)(seltok + (long long)(b*256+slot)*1024))[tid] = val;
}

__global__ void attn_softmax(u16* __restrict__ S, const int* __restrict__ neff){
  const int ri = blockIdx.x*4 + (threadIdx.x>>6);
  const int lane = threadIdx.x & 63;
  const int b = ri >> 14;
  const int ne = neff[b];
  u16* p = S + (long long)ri*256 + lane*4;
  if (ne == 0){ uint2 zz; zz.x=0u; zz.y=0u; *(uint2*)p = zz; return; }
  uint2 raw = *(const uint2*)p;
  u16 uu[4] = {(u16)(raw.x&0xffffu),(u16)(raw.x>>16),(u16)(raw.y&0xffffu),(u16)(raw.y>>16)};
  float xs[4];
  #pragma unroll
  for (int q2=0;q2<4;q2++){ const int tt = lane*4+q2; xs[q2] = (tt<ne)? b2f(uu[q2]) : -1e30f; }
  float mx = fmaxf(fmaxf(xs[0],xs[1]),fmaxf(xs[2],xs[3]));
  mx = waveRedMax(mx);
  float e[4]; float sm=0.f;
  #pragma unroll
  for (int q2=0;q2<4;q2++){ e[q2] = (lane*4+q2<ne)? expf(xs[q2]-mx) : 0.f; sm += e[q2]; }
  sm = waveRedSum(sm);
  const float inv = 1.f/sm;
  #pragma unroll
  for (int q2=0;q2<4;q2++) uu[q2] = f2b(e[q2]*inv);
  raw.x = (u32)uu[0] | ((u32)uu[1]<<16);
  raw.y = (u32)uu[2] | ((u32)uu[3]<<16);
  *(uint2*)p = raw;
}

__global__ void final_ln(const float* __restrict__ x, const u16* __restrict__ fused,
                         const float* __restrict__ g, const float* __restrict__ bb,
                         const int* __restrict__ anyv, float* __restrict__ out){
  const int row = blockIdx.x; const int b = row>>11; const int tid = threadIdx.x;
  const float4 xv = ((const float4*)(x + (long long)row*1024))[tid];
  const uint2 fv = ((const uint2*)(fused + (long long)row*1024))[tid];
  const float e0 = xv.x + b2f((u16)(fv.x&0xffffu));
  const float e1 = xv.y + b2f((u16)(fv.x>>16));
  const float e2 = xv.z + b2f((u16)(fv.y&0xffffu));
  const float e3 = xv.w + b2f((u16)(fv.y>>16));
  const float mean = blockRedSum(e0+e1+e2+e3) * (1.f/1024.f);
  const float d0=e0-mean, d1=e1-mean, d2=e2-mean, d3=e3-mean;
  const float var = blockRedSum(d0*d0+d1*d1+d2*d2+d3*d3) * (1.f/1024.f);
  const float inv = rsqrtf(var + 1e-5f);
  const float4 gv = ((const float4*)g)[tid];
  const float4 bv = ((const float4*)bb)[tid];
  float4 o;
  if (anyv[b]){
    o.x = d0*inv*gv.x + bv.x; o.y = d1*inv*gv.y + bv.y;
    o.z = d2*inv*gv.z + bv.z; o.w = d3*inv*gv.w + bv.w;
  } else o = xv;
  ((float4*)(out + (long long)row*1024))[tid] = o;
}

// ============================================================================
extern "C" void kernel_launch(void* const* d_in, const int* in_sizes, int n_in,
                              void* d_out, int out_size, void* d_ws, size_t ws_size,
                              hipStream_t stream) {
  (void)in_sizes; (void)n_in;
  const float* x      = (const float*)d_in[0];
  const float* retr   = (const float*)d_in[1];
  const float* qg_w1  = (const float*)d_in[2];
  const float* qg_b1  = (const float*)d_in[3];
  const float* qg_w2  = (const float*)d_in[4];
  const float* qg_b2  = (const float*)d_in[5];
  const float* pln_g  = (const float*)d_in[6];
  const float* pln_b  = (const float*)d_in[7];
  const float* pool_w = (const float*)d_in[8];
  const float* pool_b = (const float*)d_in[9];
  const float* rel_w1 = (const float*)d_in[10];
  const float* rel_b1 = (const float*)d_in[11];
  const float* rel_w2 = (const float*)d_in[12];
  const float* rel_b2 = (const float*)d_in[13];
  const float* in_w   = (const float*)d_in[14];
  const float* in_b   = (const float*)d_in[15];
  const float* out_w  = (const float*)d_in[16];
  const float* out_b  = (const float*)d_in[17];
  const float* fln_g  = (const float*)d_in[18];
  const float* fln_b  = (const float*)d_in[19];
  float* out = (float*)d_out;
  char* ws = (char*)d_ws;

  const size_t MB = 1u<<20;
  const size_t REQUIRED = 131*MB;
  if (ws_size < REQUIRED){
    ws_report<<<(out_size/4 + 255)/256, 256, 0, stream>>>(out, out_size/4, (float)(ws_size>>20));
    return;
  }

  // ---- layout per header comment ----
  u16* qg1Th = (u16*)(ws + 0*MB);        // [P->A]
  u16* qg1Tl = (u16*)(ws + 6*MB);
  u16* qg2Th = (u16*)(ws + 12*MB);
  u16* qg2Tl = (u16*)(ws + 18*MB);
  u16* xh    = (u16*)(ws + 24*MB);       // [P->A,F]
  u16* xl    = (u16*)(ws + 40*MB);       // [P->A]
  u16* qfh   = (u16*)(ws + 56*MB);       // per-retriever [A->B]
  u16* qfl   = (u16*)(ws + 72*MB);
  u16* t1h   = (u16*)(ws + 88*MB);       // [A scratch]
  u16* t1l   = (u16*)(ws + 96*MB);
  float* scoresA = (float*)(ws + 88*MB); // [B] over dead t1
  float* scoresB = (float*)(ws + 104*MB);// [B]
  // stage D/E overlays (qg weights dead after stage A):
  u16* rh    = (u16*)(ws + 0*MB);        // 6  [D,E]
  u16* rl    = (u16*)(ws + 6*MB);        // 6  [D]
  u16* relTh = (u16*)(ws + 12*MB);       // 1  [D]
  u16* relTl = (u16*)(ws + 13*MB);       // 1  [D]
  u16* seltok= (u16*)(ws + 14*MB);       // 2  [E->F vproj]
  u16* kbuf  = (u16*)(ws + 16*MB);       // 2  [F, dead after QK^T]
  u16* VT    = (u16*)(ws + 18*MB);       // 2  [F, dead after AV]
  float* hbuf= (float*)(ws + 88*MB);     // 6  [D] over dead scoresA
  // stage F overlays:
  u16* inT   = (u16*)(ws + 40*MB);       // 6  over dead xl
  u16* outT  = (u16*)(ws + 46*MB);       // 2
  u16* qbuf  = (u16*)(ws + 56*MB);       // 16 over dead qfh
  u16* fused = (u16*)(ws + 72*MB);       // 16 over dead qfl
  u16* Sattn = (u16*)(ws + 88*MB);       // 32 over dead scores
  u16* attnout=(u16*)(ws + 0*MB);        // 16 over dead rh/rl/relT/seltok
  char* SM = ws + 120*MB;
  float* wbuf    = (float*)(SM);            // 96 KB [12][2048]
  float* pooledB = (float*)(SM + 98304);    // 48 KB
  float* plbuf   = (float*)(SM + 147456);   // 48 KB
  float* queries = (float*)(SM + 196608);   // 48 KB
  float* qpart   = (float*)(SM + 245760);   // 24 KB
  float* relv    = (float*)(SM + 270336);   // 12 KB
  int*   selidx  = (int*)(SM + 282624);
  int*   neff    = (int*)(SM + 286720);
  int*   anyv    = (int*)(SM + 286784);
  float* mrow0   = (float*)(SM + 286848);
  float* drow0   = (float*)(SM + 295040);
  float* mrow1   = (float*)(SM + 303232);
  float* drow1   = (float*)(SM + 311424);

  dim3 b256(256);
  dim3 tb(32,8);
  const long long SCZ = (long long)(16*MB)/4;   // scoresA -> scoresB (4,194,304 floats)

  // --- prep ---
  split_transpose_w<<<dim3(32,32,3), tb, 0, stream>>>(qg_w1, qg1Th, qg1Tl, 1024, 1024);
  split_transpose_w<<<dim3(32,32,3), tb, 0, stream>>>(qg_w2, qg2Th, qg2Tl, 1024, 1024);
  split_f32_k<<<8192, b256, 0, stream>>>(x, xh, xl, 2097152);
  zero_f32<<<144, b256, 0, stream>>>(wbuf, 36864);   // wbuf + pooledB

  // --- stages A+B interleaved per retriever (qf reused; 16 MB each half) ---
  for (int r = 0; r < 3; r++){
    const long long wo = (long long)r*1048576;
    for (int hf = 0; hf < 2; hf++){
      const long long xo = (long long)hf*4194304;   // 4096 rows * 1024
      gemm_nt_split<SP_GELU_SPLIT><<<dim3(8,32,1), b256, 0, stream>>>(
          xh+xo, xl+xo, 1024, 0,  qg1Th+wo, qg1Tl+wo, 1024, 0,
          t1h, t1l, 1024, 0,  qg_b1+r*1024, 1.f, 1024);
      gemm_nt_split<SP_BIAS_SPLIT><<<dim3(8,32,1), b256, 0, stream>>>(
          t1h, t1l, 1024, 0,  qg2Th+wo, qg2Tl+wo, 1024, 0,
          qfh+xo, qfl+xo, 1024, 0,  qg_b2+r*1024, 1.f, 1024);
    }
    for (int p2 = 0; p2 < 2; p2++){
      const long long qo = (long long)(p2*2)*2097152;
      gemm_nt_split<SP_SCALE_F32><<<dim3(16,16,2), b256, 0, stream>>>(
          qfh+qo, qfl+qo, 1024, 2097152,  qfh+qo, qfl+qo, 1024, 2097152,
          scoresA, nullptr, 2048, SCZ,  nullptr, 0.03125f, 1024);
      row_stats_f32<<<2048, b256, 0, stream>>>(scoresA, mrow0, drow0);
      row_stats_f32<<<2048, b256, 0, stream>>>(scoresB, mrow1, drow1);
      col_mean_f32<<<dim3(8,32), b256, 0, stream>>>(scoresA, mrow0, drow0, wbuf + (r*4+p2*2  )*2048);
      col_mean_f32<<<dim3(8,32), b256, 0, stream>>>(scoresB, mrow1, drow1, wbuf + (r*4+p2*2+1)*2048);
    }
    pooled_par<<<dim3(4,16), b256, 0, stream>>>(qfh, qfl, wbuf + r*8192, pooledB + r*4096);
  }
  pool_ln<<<12, 1024, 0, stream>>>(pooledB, pln_g, pln_b, plbuf);
  init_queries<<<48, b256, 0, stream>>>(pool_b, queries);
  query_accum<<<dim3(12,32), b256, 0, stream>>>(plbuf, pool_w, queries);

  // --- stage D prep (qg weights dead now) + relevance scorer ---
  split_f32_k<<<3072, b256, 0, stream>>>(retr, rh, rl, 786432);
  split_transpose_w<<<dim3(16,32,1), tb, 0, stream>>>(rel_w1, relTh, relTl, 1024, 512);
  init_qpart<<<24, b256, 0, stream>>>(rel_b1, qpart);
  qpart_accum<<<dim3(12,16), b256, 0, stream>>>(queries, rel_w1, qpart);
  gemm_nt_split<SP_QBG_F32><<<dim3(4,24,1), b256, 0, stream>>>(
      rh, rl, 1024, 0,  relTh, relTl, 1024, 0,  hbuf, nullptr, 512, 0,  qpart, 1.f, 1024);
  rel_score_f32<<<768, b256, 0, stream>>>(hbuf, rel_w2, rel_b2, relv);

  // --- stage E ---
  select_topk<<<4, 768, 0, stream>>>(relv, selidx, neff, anyv);
  gather_sel<<<dim3(256,4), b256, 0, stream>>>(rh, selidx, neff, seltok);

  // --- stage F ---
  transpose_w<<<dim3(32,32,3), tb, 0, stream>>>(in_w,  inT,  1024, 1024);
  transpose_w<<<dim3(32,32,1), tb, 0, stream>>>(out_w, outT, 1024, 1024);
  gemm_nt<EPI_BIAS><<<dim3(8,64,1), b256, 0, stream>>>(
      xh,1024,0,0,  inT,1024,0,0,  qbuf,1024,0,0,  in_b,0, 1.f, 1024, 1);
  gemm_nt<EPI_BIAS><<<dim3(8,8,1), b256, 0, stream>>>(
      seltok,1024,0,0,  inT+1048576,1024,0,0,  kbuf,1024,0,0,  in_b+1024,0, 1.f, 1024, 1);
  gemm_nt<EPI_VT><<<dim3(8,8,1), b256, 0, stream>>>(
      seltok,1024,0,0,  inT+2097152,1024,0,0,  VT,0,0,0,  in_b+2048,0, 1.f, 1024, 1);
  gemm_nt<EPI_SCALE><<<dim3(2,16,32), b256, 0, stream>>>(
      qbuf,1024,2097152,128,  kbuf,1024,262144,128,  Sattn,256,4194304,524288,
      (const float*)nullptr,0, 0.08838834764831845f, 128, 8);
  attn_softmax<<<16384, b256, 0, stream>>>(Sattn, neff);
  gemm_nt<EPI_NONE><<<dim3(1,16,32), b256, 0, stream>>>(
      Sattn,256,4194304,524288,  VT,256,262144,32768,  attnout,1024,2097152,128,
      (const float*)nullptr,0, 1.f, 256, 8);
  gemm_nt<EPI_BIAS><<<dim3(8,64,1), b256, 0, stream>>>(
      attnout,1024,0,0,  outT,1024,0,0,  fused,1024,0,0,  out_b,0, 1.f, 1024, 1);
  final_ln<<<8192, b256, 0, stream>>>(x, fused, fln_g, fln_b, anyv, out);
}